// Round 6
// baseline (100.655 us; speedup 1.0000x reference)
//
#include <hip/hip_runtime.h>
#include <cmath>

#define EPSBN 1e-5f

namespace {
constexpr int C_IN = 512;
constexpr int CC   = 64;
constexpr int CD   = 8;
constexpr int HW   = 256;
constexpr int DHW  = CD * HW;        // 2048
constexpr int QSZ  = 2 * CC * DHW;   // 262144 floats per q/k/v buffer

// padded input layout for conv: [n 2][dp 10][g 8][row 18][col 18][cil 8] bf16
constexpr int PG    = 18 * 18;           // 324
constexpr int GPLN  = PG * 8;            // 2592 elems per (dp,g) plane
constexpr int PADSZ = 2 * 10 * 8 * GPLN; // 414720 elems per branch
// Wt layout: [branch][tap 27][co 512][ci 64] bf16
constexpr int WTSZ  = 27 * 512 * 64;

typedef __attribute__((ext_vector_type(8))) short bf16x8;
typedef __attribute__((ext_vector_type(4))) float f32x4;

__device__ inline unsigned short f2bf(float f) {
    unsigned u = __float_as_uint(f);
    return (unsigned short)((u + 0x7fffu + ((u >> 16) & 1u)) >> 16);
}
}

// ---------------------------------------------------------------------------
// prep: [0,405) zero pads | [405,1429) weight transpose | [1429,1621) Wqkv
// ---------------------------------------------------------------------------
__global__ __launch_bounds__(256) void prep_kernel(
    const float* __restrict__ Ws, const float* __restrict__ Wd,
    const float* __restrict__ Wq, const float* __restrict__ Wk,
    const float* __restrict__ Wv,
    uint4* __restrict__ pads, unsigned short* __restrict__ Wt,
    unsigned short* __restrict__ Wqkv)
{
    int bid = blockIdx.x;
    int t = threadIdx.x;
    if (bid < 405) {
        pads[bid * 256 + t] = make_uint4(0, 0, 0, 0);
    } else if (bid < 1429) {
        int b2 = bid - 405;
        int b  = b2 >> 9;
        int co = b2 & 511;
        const float* W = b ? Wd : Ws;
        unsigned short* o = Wt + (size_t)b * WTSZ;
        for (int k = t; k < 27 * 64; k += 256) {
            int tap = k >> 6, ci = k & 63;
            float w = W[((size_t)co * 64 + ci) * 27 + tap];
            o[((size_t)tap * 512 + co) * 64 + ci] = f2bf(w);
        }
    } else {
        int co = bid - 1429;          // 0..191
        const float* W = co < 64 ? Wq : co < 128 ? Wk : Wv;
        int c = co & 63;
        for (int ci = t; ci < 512; ci += 256)
            Wqkv[(size_t)co * 512 + ci] = f2bf(W[(size_t)c * 512 + ci]);
    }
}

// ---------------------------------------------------------------------------
// fused transpose + MFMA GEMM for q/k/v (+BN+ReLU).
// grid = 256 (2 n x 128 pos-tiles of 16); block 256 thr = 4 waves.
// ---------------------------------------------------------------------------
__global__ __launch_bounds__(256) void qkv_gemm_kernel(
    const float* __restrict__ x, const unsigned short* __restrict__ Wqkv,
    const float* __restrict__ bq, const float* __restrict__ gq,
    const float* __restrict__ btq, const float* __restrict__ mq,
    const float* __restrict__ vq,
    const float* __restrict__ bk, const float* __restrict__ gk,
    const float* __restrict__ btk, const float* __restrict__ mk,
    const float* __restrict__ vk,
    const float* __restrict__ bv, const float* __restrict__ gv,
    const float* __restrict__ btv, const float* __restrict__ mv,
    const float* __restrict__ vv,
    float* __restrict__ outq, float* __restrict__ outk, float* __restrict__ outv)
{
    int bid = blockIdx.x;
    int n = bid >> 7, p0 = (bid & 127) * 16;

    __shared__ __align__(16) unsigned short xs[16 * 512];   // 16 KB
    int t = threadIdx.x;

    const float* xb = x + ((size_t)n * C_IN) * DHW + p0;
#pragma unroll
    for (int pass = 0; pass < 8; ++pass) {
        int idx = pass * 256 + t;          // 0..2047
        int ci = idx >> 2, pq = idx & 3;
        float4 v4 = *reinterpret_cast<const float4*>(xb + (size_t)ci * DHW + pq * 4);
        float arr[4] = {v4.x, v4.y, v4.z, v4.w};
#pragma unroll
        for (int u = 0; u < 4; ++u) {
            int pos = pq * 4 + u;
            int boff = pos * 1024 + ((ci * 2) ^ ((pos & 7) << 4));
            *reinterpret_cast<unsigned short*>(
                reinterpret_cast<char*>(xs) + boff) = f2bf(arr[u]);
        }
    }
    __syncthreads();

    int wid = t >> 6, lane = t & 63;
    int l15 = lane & 15, l4 = lane >> 4;
    int mh = wid * 3;
    int pos = l15;

    bf16x8 bfr[16];
    const char* xsb = reinterpret_cast<const char*>(xs) + pos * 1024;
    int swz = (pos & 7) << 4;
#pragma unroll
    for (int kk = 0; kk < 16; ++kk)
        bfr[kk] = *reinterpret_cast<const bf16x8*>(xsb + ((kk * 64 + l4 * 16) ^ swz));

    f32x4 acc[3];
#pragma unroll
    for (int i = 0; i < 3; ++i) acc[i] = (f32x4){0.f, 0.f, 0.f, 0.f};

#pragma unroll
    for (int i = 0; i < 3; ++i) {
        const unsigned short* wrow =
            Wqkv + ((size_t)(mh + i) * 16 + l15) * 512 + l4 * 8;
#pragma unroll
        for (int kk = 0; kk < 16; ++kk) {
            bf16x8 af = *reinterpret_cast<const bf16x8*>(wrow + kk * 32);
            acc[i] = __builtin_amdgcn_mfma_f32_16x16x32_bf16(af, bfr[kk], acc[i], 0, 0, 0);
        }
    }

#pragma unroll
    for (int i = 0; i < 3; ++i) {
        int mf = mh + i;
        int br = mf >> 2;
        const float* bb  = br == 0 ? bq  : br == 1 ? bk  : bv;
        const float* gg  = br == 0 ? gq  : br == 1 ? gk  : gv;
        const float* bt  = br == 0 ? btq : br == 1 ? btk : btv;
        const float* mm  = br == 0 ? mq  : br == 1 ? mk  : mv;
        const float* vvp = br == 0 ? vq  : br == 1 ? vk  : vv;
        float*       op  = br == 0 ? outq : br == 1 ? outk : outv;
        int cb = (mf & 3) * 16 + l4 * 4;
#pragma unroll
        for (int r = 0; r < 4; ++r) {
            int c = cb + r;
            float s = gg[c] * rsqrtf(vvp[c] + EPSBN);
            float val = (acc[i][r] + bb[c] - mm[c]) * s + bt[c];
            op[((size_t)(n * CC + c)) * DHW + p0 + pos] = fmaxf(val, 0.f);
        }
    }
}

// ---------------------------------------------------------------------------
// attention (merged): blocks [0,1024) = spatial patt; [1024,1152) = datt.
// ---------------------------------------------------------------------------
__global__ __launch_bounds__(256) void att_kernel(
    const float* __restrict__ q, const float* __restrict__ k,
    const float* __restrict__ v,
    unsigned short* __restrict__ Pp, unsigned short* __restrict__ Dp)
{
    __shared__ float sk[256], sq[256], sw[256], red[4];
    int t = threadIdx.x;
    int bid = blockIdx.x;

    if (bid < 1024) {
        int n = bid >> 9, c = (bid >> 3) & 63, d = bid & 7;
        size_t base = (size_t)bid * HW;
        float kt = k[base + t];
        float qt = q[base + t];
        float vt = v[base + t];
        sk[t] = kt;
        sq[t] = qt;

        float m = kt;
#pragma unroll
        for (int off = 32; off >= 1; off >>= 1)
            m = fmaxf(m, __shfl_xor(m, off));
        if ((t & 63) == 0) red[t >> 6] = m;
        __syncthreads();
        float kmax = fmaxf(fmaxf(red[0], red[1]), fmaxf(red[2], red[3]));

        float qkm = qt * kmax;
        float d0 = 0.f, d1 = 0.f, d2 = 0.f, d3 = 0.f;
        for (int j = 0; j < 256; j += 4) {
            d0 += __expf(fmaf(qt, sk[j + 0], -qkm));
            d1 += __expf(fmaf(qt, sk[j + 1], -qkm));
            d2 += __expf(fmaf(qt, sk[j + 2], -qkm));
            d3 += __expf(fmaf(qt, sk[j + 3], -qkm));
        }
        float den = (d0 + d1) + (d2 + d3);
        sw[t] = vt / den;
        __syncthreads();

        float kjm = kt - kmax;
        float o0 = 0.f, o1 = 0.f, o2 = 0.f, o3 = 0.f;
        for (int i = 0; i < 256; i += 4) {
            o0 += sw[i + 0] * __expf(sq[i + 0] * kjm);
            o1 += sw[i + 1] * __expf(sq[i + 1] * kjm);
            o2 += sw[i + 2] * __expf(sq[i + 2] * kjm);
            o3 += sw[i + 3] * __expf(sq[i + 3] * kjm);
        }
        float o = (o0 + o1) + (o2 + o3);

        int h = t >> 4, w = t & 15;
        size_t dst = ((((size_t)(n * 10 + d + 1) * 8 + (c >> 3)) * PG)
                      + (h + 1) * 18 + (w + 1)) * 8 + (c & 7);
        Pp[dst] = f2bf(o);
    } else {
        int g = (bid - 1024) * 256 + t;
        int nc = g >> 8, hw = g & 255;
        int n = nc >> 6, c = nc & 63;
        size_t base = (size_t)nc * DHW + hw;

        float qv[8], kv[8], vv_[8];
#pragma unroll
        for (int d = 0; d < 8; ++d) {
            qv[d]  = q[base + d * HW];
            kv[d]  = k[base + d * HW];
            vv_[d] = v[base + d * HW];
        }
        float kmax = 0.f;
#pragma unroll
        for (int d = 0; d < 8; ++d) kmax = fmaxf(kmax, kv[d]);

        float wgt[8];
#pragma unroll
        for (int i = 0; i < 8; ++i) {
            float den = 0.f, qkm = qv[i] * kmax;
#pragma unroll
            for (int j = 0; j < 8; ++j)
                den += __expf(fmaf(qv[i], kv[j], -qkm));
            wgt[i] = vv_[i] / den;
        }
        int h = hw >> 4, w = hw & 15;
#pragma unroll
        for (int j = 0; j < 8; ++j) {
            float o = 0.f, kjm = kv[j] - kmax;
#pragma unroll
            for (int i = 0; i < 8; ++i)
                o += wgt[i] * __expf(qv[i] * kjm);
            size_t dst = ((((size_t)(n * 10 + j + 1) * 8 + (c >> 3)) * PG)
                          + (h + 1) * 18 + (w + 1)) * 8 + (c & 7);
            Dp[dst] = f2bf(o);
        }
    }
}

// ---------------------------------------------------------------------------
// fused dual-branch MFMA conv + BN + ReLU + gama*(a+b) + x.
// grid = 512 = 16 ct x 16 slice x 2 pos-groups (8 h-rows each).
// LDS = 34.5 KB (10-row slab) -> 4 blocks/CU co-resident (16 waves/CU),
// independent blocks overlap phase barriers and weight-load latency.
// 4 phases: (branch, ci-half). Wave covers 2 h-rows (nt=2).
// ---------------------------------------------------------------------------
__global__ __launch_bounds__(256, 4) void conv_fused_kernel(
    const unsigned short* __restrict__ Pp, const unsigned short* __restrict__ Dp,
    const unsigned short* __restrict__ Wt,
    const float* __restrict__ bs, const float* __restrict__ gs,
    const float* __restrict__ bts, const float* __restrict__ ms,
    const float* __restrict__ vs,
    const float* __restrict__ bd, const float* __restrict__ gd,
    const float* __restrict__ btd, const float* __restrict__ md,
    const float* __restrict__ vd,
    const float* __restrict__ x, const float* __restrict__ gama,
    float* __restrict__ out)
{
    int bid = blockIdx.x;
    int pg = bid & 1;
    int sl = (bid >> 1) & 15;
    int ct = bid >> 5;            // 0..15
    int n = sl >> 3, d = sl & 7;

    // [dp 3][g 4][rl 10][col 18][ci 8] bf16 = 17280 elems = 34560 B
    __shared__ __align__(16) unsigned short lds[3 * 4 * 1440];

    int t = threadIdx.x;
    int wid = t >> 6, lane = t & 63;
    int l15 = lane & 15, l4 = lane >> 4;

    f32x4 acc[2][2][2];   // [branch][mt][nt]
#pragma unroll
    for (int b = 0; b < 2; ++b)
#pragma unroll
        for (int mt = 0; mt < 2; ++mt)
#pragma unroll
            for (int nt = 0; nt < 2; ++nt)
                acc[b][mt][nt] = (f32x4){0.f, 0.f, 0.f, 0.f};

#pragma unroll
    for (int phase = 0; phase < 4; ++phase) {
        int br = phase >> 1, half = phase & 1;
        const unsigned short* In = br ? Dp : Pp;
        __syncthreads();
        // stage 10-row slab: 12 (dp,g) planes x 180 uint4 = 2160 uint4
        for (int it = 0; it < 9; ++it) {
            int idx = it * 256 + t;
            if (idx < 2160) {
                int plane = idx / 180;       // 0..11
                int rem   = idx - plane * 180;
                int dp = plane >> 2, g = plane & 3;
                const uint4* srcp = reinterpret_cast<const uint4*>(
                    In + ((size_t)((n * 10 + d + dp) * 8 + half * 4 + g)) * GPLN)
                    + pg * 144 + rem;
                reinterpret_cast<uint4*>(lds)[idx] = *srcp;
            }
        }
        __syncthreads();

        const unsigned short* W = Wt + (size_t)br * WTSZ;
#pragma unroll
        for (int kd = 0; kd < 3; ++kd) {
            // hoist 12 B-granules: 4 local rows x 3 kw, reused across (nt,kh)
            bf16x8 g[4][3];
#pragma unroll
            for (int rr = 0; rr < 4; ++rr)
#pragma unroll
                for (int kw = 0; kw < 3; ++kw)
                    g[rr][kw] = *reinterpret_cast<const bf16x8*>(
                        &lds[(kd * 4 + l4) * 1440 + ((wid * 2 + rr) * 18 + l15 + kw) * 8]);

#pragma unroll
            for (int kh = 0; kh < 3; ++kh) {
#pragma unroll
                for (int kw = 0; kw < 3; ++kw) {
                    int tap = (kd * 3 + kh) * 3 + kw;
                    const unsigned short* wb =
                        W + ((size_t)tap * 512 + ct * 32 + l15) * 64 + half * 32 + l4 * 8;
                    bf16x8 af0 = *reinterpret_cast<const bf16x8*>(wb);
                    bf16x8 af1 = *reinterpret_cast<const bf16x8*>(wb + 16 * 64);
#pragma unroll
                    for (int nt = 0; nt < 2; ++nt) {
                        acc[br][0][nt] = __builtin_amdgcn_mfma_f32_16x16x32_bf16(
                            af0, g[nt + kh][kw], acc[br][0][nt], 0, 0, 0);
                        acc[br][1][nt] = __builtin_amdgcn_mfma_f32_16x16x32_bf16(
                            af1, g[nt + kh][kw], acc[br][1][nt], 0, 0, 0);
                    }
                }
            }
        }
    }

    // fused epilogue
    float gm = gama[0];
#pragma unroll
    for (int mt = 0; mt < 2; ++mt) {
#pragma unroll
        for (int r = 0; r < 4; ++r) {
            int co = ct * 32 + mt * 16 + l4 * 4 + r;
            float sS = gs[co] * rsqrtf(vs[co] + EPSBN);
            float oS = bs[co] - ms[co];
            float tS = bts[co];
            float sD = gd[co] * rsqrtf(vd[co] + EPSBN);
            float oD = bd[co] - md[co];
            float tD = btd[co];
#pragma unroll
            for (int nt = 0; nt < 2; ++nt) {
                int h = pg * 8 + wid * 2 + nt;
                size_t oi = ((size_t)(n * 512 + co)) * 2048 + d * 256 + h * 16 + l15;
                float rp = fmaxf((acc[0][mt][nt][r] + oS) * sS + tS, 0.f);
                float rd = fmaxf((acc[1][mt][nt][r] + oD) * sD + tD, 0.f);
                out[oi] = gm * (rp + rd) + x[oi];
            }
        }
    }
}

// ---------------------------------------------------------------------------
extern "C" void kernel_launch(void* const* d_in, const int* in_sizes, int n_in,
                              void* d_out, int out_size, void* d_ws, size_t ws_size,
                              hipStream_t stream)
{
    const float* x    = (const float*)d_in[0];
    const float* gama = (const float*)d_in[1];
    const float* Wq  = (const float*)d_in[2];
    const float* bq  = (const float*)d_in[3];
    const float* gq  = (const float*)d_in[4];
    const float* btq = (const float*)d_in[5];
    const float* mq  = (const float*)d_in[6];
    const float* vq  = (const float*)d_in[7];
    const float* Wk  = (const float*)d_in[8];
    const float* bk  = (const float*)d_in[9];
    const float* gk  = (const float*)d_in[10];
    const float* btk = (const float*)d_in[11];
    const float* mk  = (const float*)d_in[12];
    const float* vk  = (const float*)d_in[13];
    const float* Wv  = (const float*)d_in[14];
    const float* bv  = (const float*)d_in[15];
    const float* gv  = (const float*)d_in[16];
    const float* btv = (const float*)d_in[17];
    const float* mv  = (const float*)d_in[18];
    const float* vv  = (const float*)d_in[19];
    const float* Ws  = (const float*)d_in[20];
    const float* bs  = (const float*)d_in[21];
    const float* gs  = (const float*)d_in[22];
    const float* bts = (const float*)d_in[23];
    const float* ms  = (const float*)d_in[24];
    const float* vs  = (const float*)d_in[25];
    const float* Wd  = (const float*)d_in[26];
    const float* bd  = (const float*)d_in[27];
    const float* gd  = (const float*)d_in[28];
    const float* btd = (const float*)d_in[29];
    const float* md  = (const float*)d_in[30];
    const float* vd  = (const float*)d_in[31];

    char* ws = (char*)d_ws;
    unsigned short* Pp   = (unsigned short*)ws;                 // 829440 B
    unsigned short* Dp   = Pp + PADSZ;                          // 829440 B
    unsigned short* Wt   = Dp + PADSZ;                          // 3538944 B
    unsigned short* Wqkv = Wt + 2 * WTSZ;                       // 196608 B
    float* q = (float*)(ws + 5394432);
    float* k = q + QSZ;
    float* v = k + QSZ;

    prep_kernel<<<1621, 256, 0, stream>>>(Ws, Wd, Wq, Wk, Wv,
                                          (uint4*)Pp, Wt, Wqkv);

    qkv_gemm_kernel<<<256, 256, 0, stream>>>(
        x, Wqkv,
        bq, gq, btq, mq, vq,
        bk, gk, btk, mk, vk,
        bv, gv, btv, mv, vv,
        q, k, v);

    att_kernel<<<1152, 256, 0, stream>>>(q, k, v, Pp, Dp);

    conv_fused_kernel<<<512, 256, 0, stream>>>(
        Pp, Dp, Wt,
        bs, gs, bts, ms, vs,
        bd, gd, btd, md, vd,
        x, gama, (float*)d_out);
}

// Round 7
// 82.999 us; speedup vs baseline: 1.2127x; 1.2127x over previous
//
#include <hip/hip_runtime.h>
#include <cmath>

#define EPSBN 1e-5f

namespace {
constexpr int C_IN = 512;
constexpr int CC   = 64;
constexpr int CD   = 8;
constexpr int HW   = 256;
constexpr int DHW  = CD * HW;        // 2048
constexpr int QSZ  = 2 * CC * DHW;   // 262144 floats per q/k/v buffer

// padded input layout for conv: [n 2][dp 10][g 8][row 18][col 18][cil 8] bf16
constexpr int PG    = 18 * 18;           // 324
constexpr int GPLN  = PG * 8;            // 2592 elems per (dp,g) plane
constexpr int PADSZ = 2 * 10 * 8 * GPLN; // 414720 elems per branch
// Wt layout: [branch][ct 16][half 2][kd 3] chunks of [tapk 9][co 32][ci 32]
// (ci granule-of-8 position XOR-swizzled by (co ^ co>>2)&3)
constexpr int WTSZ  = 27 * 512 * 64;     // 884736 elems per branch

typedef __attribute__((ext_vector_type(8))) short bf16x8;
typedef __attribute__((ext_vector_type(4))) float f32x4;

typedef unsigned int u32_g __attribute__((address_space(1)));
typedef unsigned int u32_l __attribute__((address_space(3)));

__device__ inline unsigned short f2bf(float f) {
    unsigned u = __float_as_uint(f);
    return (unsigned short)((u + 0x7fffu + ((u >> 16) & 1u)) >> 16);
}
}

// ---------------------------------------------------------------------------
// prep: [0,405) zero pads | [405,1429) weight transpose+swizzle | [1429,1621) Wqkv
// ---------------------------------------------------------------------------
__global__ __launch_bounds__(256) void prep_kernel(
    const float* __restrict__ Ws, const float* __restrict__ Wd,
    const float* __restrict__ Wq, const float* __restrict__ Wk,
    const float* __restrict__ Wv,
    uint4* __restrict__ pads, unsigned short* __restrict__ Wt,
    unsigned short* __restrict__ Wqkv)
{
    int bid = blockIdx.x;
    int t = threadIdx.x;
    if (bid < 405) {
        pads[bid * 256 + t] = make_uint4(0, 0, 0, 0);
    } else if (bid < 1429) {
        int b2 = bid - 405;
        int b  = b2 >> 9;
        int co = b2 & 511;
        const float* W = b ? Wd : Ws;
        int ct = co >> 5, co_l = co & 31;
        int sw = (co_l ^ (co_l >> 2)) & 3;
        unsigned short* o = Wt + (size_t)b * WTSZ;
        for (int k = t; k < 27 * 64; k += 256) {
            int tap = k >> 6, ci = k & 63;
            int kd = tap / 9, tapk = tap - kd * 9;
            int half = ci >> 5, cl = ci & 31;
            int gq = cl >> 3, cin = cl & 7;
            float w = W[((size_t)co * 64 + ci) * 27 + tap];
            size_t dst = (size_t)((ct * 2 + half) * 3 + kd) * 9216
                       + tapk * 1024 + co_l * 32 + ((gq ^ sw) << 3) + cin;
            o[dst] = f2bf(w);
        }
    } else {
        int co = bid - 1429;          // 0..191
        const float* W = co < 64 ? Wq : co < 128 ? Wk : Wv;
        int c = co & 63;
        for (int ci = t; ci < 512; ci += 256)
            Wqkv[(size_t)co * 512 + ci] = f2bf(W[(size_t)c * 512 + ci]);
    }
}

// ---------------------------------------------------------------------------
// fused transpose + MFMA GEMM for q/k/v (+BN+ReLU). (unchanged)
// ---------------------------------------------------------------------------
__global__ __launch_bounds__(256) void qkv_gemm_kernel(
    const float* __restrict__ x, const unsigned short* __restrict__ Wqkv,
    const float* __restrict__ bq, const float* __restrict__ gq,
    const float* __restrict__ btq, const float* __restrict__ mq,
    const float* __restrict__ vq,
    const float* __restrict__ bk, const float* __restrict__ gk,
    const float* __restrict__ btk, const float* __restrict__ mk,
    const float* __restrict__ vk,
    const float* __restrict__ bv, const float* __restrict__ gv,
    const float* __restrict__ btv, const float* __restrict__ mv,
    const float* __restrict__ vv,
    float* __restrict__ outq, float* __restrict__ outk, float* __restrict__ outv)
{
    int bid = blockIdx.x;
    int n = bid >> 7, p0 = (bid & 127) * 16;

    __shared__ __align__(16) unsigned short xs[16 * 512];   // 16 KB
    int t = threadIdx.x;

    const float* xb = x + ((size_t)n * C_IN) * DHW + p0;
#pragma unroll
    for (int pass = 0; pass < 8; ++pass) {
        int idx = pass * 256 + t;          // 0..2047
        int ci = idx >> 2, pq = idx & 3;
        float4 v4 = *reinterpret_cast<const float4*>(xb + (size_t)ci * DHW + pq * 4);
        float arr[4] = {v4.x, v4.y, v4.z, v4.w};
#pragma unroll
        for (int u = 0; u < 4; ++u) {
            int pos = pq * 4 + u;
            int boff = pos * 1024 + ((ci * 2) ^ ((pos & 7) << 4));
            *reinterpret_cast<unsigned short*>(
                reinterpret_cast<char*>(xs) + boff) = f2bf(arr[u]);
        }
    }
    __syncthreads();

    int wid = t >> 6, lane = t & 63;
    int l15 = lane & 15, l4 = lane >> 4;
    int mh = wid * 3;
    int pos = l15;

    bf16x8 bfr[16];
    const char* xsb = reinterpret_cast<const char*>(xs) + pos * 1024;
    int swz = (pos & 7) << 4;
#pragma unroll
    for (int kk = 0; kk < 16; ++kk)
        bfr[kk] = *reinterpret_cast<const bf16x8*>(xsb + ((kk * 64 + l4 * 16) ^ swz));

    f32x4 acc[3];
#pragma unroll
    for (int i = 0; i < 3; ++i) acc[i] = (f32x4){0.f, 0.f, 0.f, 0.f};

#pragma unroll
    for (int i = 0; i < 3; ++i) {
        const unsigned short* wrow =
            Wqkv + ((size_t)(mh + i) * 16 + l15) * 512 + l4 * 8;
#pragma unroll
        for (int kk = 0; kk < 16; ++kk) {
            bf16x8 af = *reinterpret_cast<const bf16x8*>(wrow + kk * 32);
            acc[i] = __builtin_amdgcn_mfma_f32_16x16x32_bf16(af, bfr[kk], acc[i], 0, 0, 0);
        }
    }

#pragma unroll
    for (int i = 0; i < 3; ++i) {
        int mf = mh + i;
        int br = mf >> 2;
        const float* bb  = br == 0 ? bq  : br == 1 ? bk  : bv;
        const float* gg  = br == 0 ? gq  : br == 1 ? gk  : gv;
        const float* bt  = br == 0 ? btq : br == 1 ? btk : btv;
        const float* mm  = br == 0 ? mq  : br == 1 ? mk  : mv;
        const float* vvp = br == 0 ? vq  : br == 1 ? vk  : vv;
        float*       op  = br == 0 ? outq : br == 1 ? outk : outv;
        int cb = (mf & 3) * 16 + l4 * 4;
#pragma unroll
        for (int r = 0; r < 4; ++r) {
            int c = cb + r;
            float s = gg[c] * rsqrtf(vvp[c] + EPSBN);
            float val = (acc[i][r] + bb[c] - mm[c]) * s + bt[c];
            op[((size_t)(n * CC + c)) * DHW + p0 + pos] = fmaxf(val, 0.f);
        }
    }
}

// ---------------------------------------------------------------------------
// attention (merged): blocks [0,1024) = spatial patt; [1024,1152) = datt.
// (unchanged)
// ---------------------------------------------------------------------------
__global__ __launch_bounds__(256) void att_kernel(
    const float* __restrict__ q, const float* __restrict__ k,
    const float* __restrict__ v,
    unsigned short* __restrict__ Pp, unsigned short* __restrict__ Dp)
{
    __shared__ float sk[256], sq[256], sw[256], red[4];
    int t = threadIdx.x;
    int bid = blockIdx.x;

    if (bid < 1024) {
        int n = bid >> 9, c = (bid >> 3) & 63, d = bid & 7;
        size_t base = (size_t)bid * HW;
        float kt = k[base + t];
        float qt = q[base + t];
        float vt = v[base + t];
        sk[t] = kt;
        sq[t] = qt;

        float m = kt;
#pragma unroll
        for (int off = 32; off >= 1; off >>= 1)
            m = fmaxf(m, __shfl_xor(m, off));
        if ((t & 63) == 0) red[t >> 6] = m;
        __syncthreads();
        float kmax = fmaxf(fmaxf(red[0], red[1]), fmaxf(red[2], red[3]));

        float qkm = qt * kmax;
        float d0 = 0.f, d1 = 0.f, d2 = 0.f, d3 = 0.f;
        for (int j = 0; j < 256; j += 4) {
            d0 += __expf(fmaf(qt, sk[j + 0], -qkm));
            d1 += __expf(fmaf(qt, sk[j + 1], -qkm));
            d2 += __expf(fmaf(qt, sk[j + 2], -qkm));
            d3 += __expf(fmaf(qt, sk[j + 3], -qkm));
        }
        float den = (d0 + d1) + (d2 + d3);
        sw[t] = vt / den;
        __syncthreads();

        float kjm = kt - kmax;
        float o0 = 0.f, o1 = 0.f, o2 = 0.f, o3 = 0.f;
        for (int i = 0; i < 256; i += 4) {
            o0 += sw[i + 0] * __expf(sq[i + 0] * kjm);
            o1 += sw[i + 1] * __expf(sq[i + 1] * kjm);
            o2 += sw[i + 2] * __expf(sq[i + 2] * kjm);
            o3 += sw[i + 3] * __expf(sq[i + 3] * kjm);
        }
        float o = (o0 + o1) + (o2 + o3);

        int h = t >> 4, w = t & 15;
        size_t dst = ((((size_t)(n * 10 + d + 1) * 8 + (c >> 3)) * PG)
                      + (h + 1) * 18 + (w + 1)) * 8 + (c & 7);
        Pp[dst] = f2bf(o);
    } else {
        int g = (bid - 1024) * 256 + t;
        int nc = g >> 8, hw = g & 255;
        int n = nc >> 6, c = nc & 63;
        size_t base = (size_t)nc * DHW + hw;

        float qv[8], kv[8], vv_[8];
#pragma unroll
        for (int d = 0; d < 8; ++d) {
            qv[d]  = q[base + d * HW];
            kv[d]  = k[base + d * HW];
            vv_[d] = v[base + d * HW];
        }
        float kmax = 0.f;
#pragma unroll
        for (int d = 0; d < 8; ++d) kmax = fmaxf(kmax, kv[d]);

        float wgt[8];
#pragma unroll
        for (int i = 0; i < 8; ++i) {
            float den = 0.f, qkm = qv[i] * kmax;
#pragma unroll
            for (int j = 0; j < 8; ++j)
                den += __expf(fmaf(qv[i], kv[j], -qkm));
            wgt[i] = vv_[i] / den;
        }
        int h = hw >> 4, w = hw & 15;
#pragma unroll
        for (int j = 0; j < 8; ++j) {
            float o = 0.f, kjm = kv[j] - kmax;
#pragma unroll
            for (int i = 0; i < 8; ++i)
                o += wgt[i] * __expf(qv[i] * kjm);
            size_t dst = ((((size_t)(n * 10 + j + 1) * 8 + (c >> 3)) * PG)
                          + (h + 1) * 18 + (w + 1)) * 8 + (c & 7);
            Dp[dst] = f2bf(o);
        }
    }
}

// ---------------------------------------------------------------------------
// fused dual-branch MFMA conv + BN + ReLU + gama*(a+b) + x.
// grid = 256 = 16 ct x 16 slice (full 16-row slice, 4 waves, nt=4).
// Weights staged in LDS via global_load_lds, double-buffered per (phase,kd)
// chunk (18.4 KB); input slab (62.6 KB, plane-padded) restaged per phase.
// Inner loop is pure ds_read_b128 + MFMA (no global loads on critical path).
// ---------------------------------------------------------------------------
__global__ __launch_bounds__(256, 1) void conv_fused_kernel(
    const unsigned short* __restrict__ Pp, const unsigned short* __restrict__ Dp,
    const unsigned short* __restrict__ Wt,
    const float* __restrict__ bs, const float* __restrict__ gs,
    const float* __restrict__ bts, const float* __restrict__ ms,
    const float* __restrict__ vs,
    const float* __restrict__ bd, const float* __restrict__ gd,
    const float* __restrict__ btd, const float* __restrict__ md,
    const float* __restrict__ vd,
    const float* __restrict__ x, const float* __restrict__ gama,
    float* __restrict__ out)
{
    int bid = blockIdx.x;
    int ct = bid & 15;            // fast index -> same-ct blocks share XCD/L2
    int sl = bid >> 4;
    int n = sl >> 3, d = sl & 7;

    // input slab: 12 planes x (2592+16 pad) shorts = 62,592 B
    __shared__ __align__(16) unsigned short lds_in[12 * 2608];
    // weight double buffer: 2 x 9216 shorts = 36,864 B  (total 99,456 B)
    __shared__ __align__(16) unsigned short lds_w[2][9216];

    int t = threadIdx.x;
    int wid = t >> 6, lane = t & 63;
    int l15 = lane & 15, l4 = lane >> 4;
    int hrow = wid * 4;
    int sw  = (l15 ^ (l15 >> 2)) & 3;
    int wgq = ((l4 ^ sw) & 3) << 3;    // swizzled granule elem offset

    f32x4 acc[2][2][4];   // [branch][mt][nt]
#pragma unroll
    for (int b = 0; b < 2; ++b)
#pragma unroll
        for (int mt = 0; mt < 2; ++mt)
#pragma unroll
            for (int nt = 0; nt < 4; ++nt)
                acc[b][mt][nt] = (f32x4){0.f, 0.f, 0.f, 0.f};

#define STAGE_IN(p_) do {                                                     \
    const int hf_ = (p_) & 1;                                                 \
    const unsigned short* In_ = ((p_) >> 1) ? Dp : Pp;                        \
    _Pragma("unroll")                                                         \
    for (int pl = 0; pl < 12; ++pl) {                                         \
        const uint4* s4 = reinterpret_cast<const uint4*>(                     \
            In_ + ((size_t)((n * 10 + d + (pl >> 2)) * 8 + hf_ * 4            \
                            + (pl & 3))) * GPLN);                             \
        uint4* d4 = reinterpret_cast<uint4*>(lds_in) + pl * 326;              \
        d4[t] = s4[t];                                                        \
        if (t < 68) d4[256 + t] = s4[256 + t];                                \
    }                                                                         \
} while (0)

#define PREF_W(c_) do {                                                       \
    const int p_ = (c_) / 3, kd_ = (c_) % 3;                                  \
    const unsigned short* src_ = Wt + (size_t)(p_ >> 1) * WTSZ                \
        + (size_t)((ct * 2 + (p_ & 1)) * 3 + kd_) * 9216;                     \
    unsigned short* db_ = &lds_w[(c_) & 1][0];                                \
    for (int i = wid; i < 18; i += 4)                                         \
        __builtin_amdgcn_global_load_lds(                                     \
            (const u32_g*)(src_ + i * 512 + lane * 8),                        \
            (u32_l*)(db_ + i * 512), 16, 0, 0);                               \
} while (0)

#define COMPUTE(c_) do {                                                      \
    const int kd_ = (c_) % 3, br_ = (c_) / 6;                                 \
    const unsigned short* wb_ = &lds_w[(c_) & 1][0];                          \
    bf16x8 gg[6][3];                                                          \
    _Pragma("unroll")                                                         \
    for (int rr = 0; rr < 6; ++rr)                                            \
        _Pragma("unroll")                                                     \
        for (int kw = 0; kw < 3; ++kw)                                        \
            gg[rr][kw] = *reinterpret_cast<const bf16x8*>(                    \
                &lds_in[(kd_ * 4 + l4) * 2608                                 \
                        + ((hrow + rr) * 18 + l15 + kw) * 8]);                \
    _Pragma("unroll")                                                         \
    for (int kh = 0; kh < 3; ++kh)                                            \
        _Pragma("unroll")                                                     \
        for (int kw = 0; kw < 3; ++kw) {                                      \
            int tapk_ = kh * 3 + kw;                                          \
            bf16x8 af0 = *reinterpret_cast<const bf16x8*>(                    \
                &wb_[tapk_ * 1024 + l15 * 32 + wgq]);                         \
            bf16x8 af1 = *reinterpret_cast<const bf16x8*>(                    \
                &wb_[tapk_ * 1024 + (16 + l15) * 32 + wgq]);                  \
            _Pragma("unroll")                                                 \
            for (int nt = 0; nt < 4; ++nt) {                                  \
                acc[br_][0][nt] = __builtin_amdgcn_mfma_f32_16x16x32_bf16(    \
                    af0, gg[nt + kh][kw], acc[br_][0][nt], 0, 0, 0);          \
                acc[br_][1][nt] = __builtin_amdgcn_mfma_f32_16x16x32_bf16(    \
                    af1, gg[nt + kh][kw], acc[br_][1][nt], 0, 0, 0);          \
            }                                                                 \
        }                                                                     \
} while (0)

    STAGE_IN(0);
    PREF_W(0);
    __syncthreads();

#pragma unroll
    for (int c = 0; c < 12; ++c) {
        if (c < 11) PREF_W(c + 1);
        COMPUTE(c);
        if (c < 11) {
            __syncthreads();                    // drains gload_lds (vmcnt)
            if (c % 3 == 2) {                   // phase boundary: restage input
                STAGE_IN(c / 3 + 1);
                __syncthreads();
            }
        }
    }

#undef STAGE_IN
#undef PREF_W
#undef COMPUTE

    // fused epilogue
    float gm = gama[0];
#pragma unroll
    for (int mt = 0; mt < 2; ++mt) {
#pragma unroll
        for (int r = 0; r < 4; ++r) {
            int co = ct * 32 + mt * 16 + l4 * 4 + r;
            float sS = gs[co] * rsqrtf(vs[co] + EPSBN);
            float oS = bs[co] - ms[co];
            float tS = bts[co];
            float sD = gd[co] * rsqrtf(vd[co] + EPSBN);
            float oD = bd[co] - md[co];
            float tD = btd[co];
#pragma unroll
            for (int nt = 0; nt < 4; ++nt) {
                int pos = wid * 64 + nt * 16 + l15;
                size_t oi = ((size_t)(n * 512 + co)) * 2048 + d * 256 + pos;
                float rp = fmaxf((acc[0][mt][nt][r] + oS) * sS + tS, 0.f);
                float rd = fmaxf((acc[1][mt][nt][r] + oD) * sD + tD, 0.f);
                out[oi] = gm * (rp + rd) + x[oi];
            }
        }
    }
}

// ---------------------------------------------------------------------------
extern "C" void kernel_launch(void* const* d_in, const int* in_sizes, int n_in,
                              void* d_out, int out_size, void* d_ws, size_t ws_size,
                              hipStream_t stream)
{
    const float* x    = (const float*)d_in[0];
    const float* gama = (const float*)d_in[1];
    const float* Wq  = (const float*)d_in[2];
    const float* bq  = (const float*)d_in[3];
    const float* gq  = (const float*)d_in[4];
    const float* btq = (const float*)d_in[5];
    const float* mq  = (const float*)d_in[6];
    const float* vq  = (const float*)d_in[7];
    const float* Wk  = (const float*)d_in[8];
    const float* bk  = (const float*)d_in[9];
    const float* gk  = (const float*)d_in[10];
    const float* btk = (const float*)d_in[11];
    const float* mk  = (const float*)d_in[12];
    const float* vk  = (const float*)d_in[13];
    const float* Wv  = (const float*)d_in[14];
    const float* bv  = (const float*)d_in[15];
    const float* gv  = (const float*)d_in[16];
    const float* btv = (const float*)d_in[17];
    const float* mv  = (const float*)d_in[18];
    const float* vv  = (const float*)d_in[19];
    const float* Ws  = (const float*)d_in[20];
    const float* bs  = (const float*)d_in[21];
    const float* gs  = (const float*)d_in[22];
    const float* bts = (const float*)d_in[23];
    const float* ms  = (const float*)d_in[24];
    const float* vs  = (const float*)d_in[25];
    const float* Wd  = (const float*)d_in[26];
    const float* bd  = (const float*)d_in[27];
    const float* gd  = (const float*)d_in[28];
    const float* btd = (const float*)d_in[29];
    const float* md  = (const float*)d_in[30];
    const float* vd  = (const float*)d_in[31];

    char* ws = (char*)d_ws;
    unsigned short* Pp   = (unsigned short*)ws;                 // 829440 B
    unsigned short* Dp   = Pp + PADSZ;                          // 829440 B
    unsigned short* Wt   = Dp + PADSZ;                          // 3538944 B
    unsigned short* Wqkv = Wt + 2 * WTSZ;                       // 196608 B
    float* q = (float*)(ws + 5394432);
    float* k = q + QSZ;
    float* v = k + QSZ;

    prep_kernel<<<1621, 256, 0, stream>>>(Ws, Wd, Wq, Wk, Wv,
                                          (uint4*)Pp, Wt, Wqkv);

    qkv_gemm_kernel<<<256, 256, 0, stream>>>(
        x, Wqkv,
        bq, gq, btq, mq, vq,
        bk, gk, btk, mk, vk,
        bv, gv, btv, mv, vv,
        q, k, v);

    att_kernel<<<1152, 256, 0, stream>>>(q, k, v, Pp, Dp);

    conv_fused_kernel<<<256, 256, 0, stream>>>(
        Pp, Dp, Wt,
        bs, gs, bts, ms, vs,
        bd, gd, btd, md, vd,
        x, gama, (float*)d_out);
}

// Round 8
// 78.027 us; speedup vs baseline: 1.2900x; 1.0637x over previous
//
#include <hip/hip_runtime.h>
#include <cmath>

#define EPSBN 1e-5f

namespace {
constexpr int C_IN = 512;
constexpr int CC   = 64;
constexpr int CD   = 8;
constexpr int HW   = 256;
constexpr int DHW  = CD * HW;        // 2048
constexpr int QSZ  = 2 * CC * DHW;   // 262144 floats per q/k/v buffer

// padded input layout for conv: [n 2][dp 10][g 8][row 18][col 18][cil 8] bf16
constexpr int PG    = 18 * 18;           // 324
constexpr int GPLN  = PG * 8;            // 2592 elems per (dp,g) plane
constexpr int PADSZ = 2 * 10 * 8 * GPLN; // 414720 elems per branch
// Wt layout: [branch][ct 16][half 2][kd 3] chunks of [tapk 9][coh 2][co16][g4][ci8]
// -> af reads are dense 1024 B blocks (conflict-free), gload_lds-linear.
constexpr int WTSZ  = 27 * 512 * 64;     // 884736 elems per branch

typedef __attribute__((ext_vector_type(8))) short bf16x8;
typedef __attribute__((ext_vector_type(4))) float f32x4;

typedef unsigned int u32_g __attribute__((address_space(1)));
typedef unsigned int u32_l __attribute__((address_space(3)));

__device__ inline unsigned short f2bf(float f) {
    unsigned u = __float_as_uint(f);
    return (unsigned short)((u + 0x7fffu + ((u >> 16) & 1u)) >> 16);
}
}

// ---------------------------------------------------------------------------
// prep: [0,405) zero pads | [405,1429) weight transpose | [1429,1621) Wqkv
// ---------------------------------------------------------------------------
__global__ __launch_bounds__(256) void prep_kernel(
    const float* __restrict__ Ws, const float* __restrict__ Wd,
    const float* __restrict__ Wq, const float* __restrict__ Wk,
    const float* __restrict__ Wv,
    uint4* __restrict__ pads, unsigned short* __restrict__ Wt,
    unsigned short* __restrict__ Wqkv)
{
    int bid = blockIdx.x;
    int t = threadIdx.x;
    if (bid < 405) {
        pads[bid * 256 + t] = make_uint4(0, 0, 0, 0);
    } else if (bid < 1429) {
        int b2 = bid - 405;
        int b  = b2 >> 9;
        int co = b2 & 511;
        const float* W = b ? Wd : Ws;
        int ct = co >> 5, co_l = co & 31;
        unsigned short* o = Wt + (size_t)b * WTSZ;
        for (int k = t; k < 27 * 64; k += 256) {
            int tap = k >> 6, ci = k & 63;
            int kd = tap / 9, tapk = tap - kd * 9;
            int half = ci >> 5, cl = ci & 31;
            int gq = cl >> 3, cin = cl & 7;
            float w = W[((size_t)co * 64 + ci) * 27 + tap];
            size_t dst = (size_t)((ct * 2 + half) * 3 + kd) * 9216
                       + tapk * 1024 + (co_l >> 4) * 512
                       + (co_l & 15) * 32 + gq * 8 + cin;
            o[dst] = f2bf(w);
        }
    } else {
        int co = bid - 1429;          // 0..191
        const float* W = co < 64 ? Wq : co < 128 ? Wk : Wv;
        int c = co & 63;
        for (int ci = t; ci < 512; ci += 256)
            Wqkv[(size_t)co * 512 + ci] = f2bf(W[(size_t)c * 512 + ci]);
    }
}

// ---------------------------------------------------------------------------
// fused transpose + MFMA GEMM for q/k/v (+BN+ReLU). (unchanged)
// ---------------------------------------------------------------------------
__global__ __launch_bounds__(256) void qkv_gemm_kernel(
    const float* __restrict__ x, const unsigned short* __restrict__ Wqkv,
    const float* __restrict__ bq, const float* __restrict__ gq,
    const float* __restrict__ btq, const float* __restrict__ mq,
    const float* __restrict__ vq,
    const float* __restrict__ bk, const float* __restrict__ gk,
    const float* __restrict__ btk, const float* __restrict__ mk,
    const float* __restrict__ vk,
    const float* __restrict__ bv, const float* __restrict__ gv,
    const float* __restrict__ btv, const float* __restrict__ mv,
    const float* __restrict__ vv,
    float* __restrict__ outq, float* __restrict__ outk, float* __restrict__ outv)
{
    int bid = blockIdx.x;
    int n = bid >> 7, p0 = (bid & 127) * 16;

    __shared__ __align__(16) unsigned short xs[16 * 512];   // 16 KB
    int t = threadIdx.x;

    const float* xb = x + ((size_t)n * C_IN) * DHW + p0;
#pragma unroll
    for (int pass = 0; pass < 8; ++pass) {
        int idx = pass * 256 + t;          // 0..2047
        int ci = idx >> 2, pq = idx & 3;
        float4 v4 = *reinterpret_cast<const float4*>(xb + (size_t)ci * DHW + pq * 4);
        float arr[4] = {v4.x, v4.y, v4.z, v4.w};
#pragma unroll
        for (int u = 0; u < 4; ++u) {
            int pos = pq * 4 + u;
            int boff = pos * 1024 + ((ci * 2) ^ ((pos & 7) << 4));
            *reinterpret_cast<unsigned short*>(
                reinterpret_cast<char*>(xs) + boff) = f2bf(arr[u]);
        }
    }
    __syncthreads();

    int wid = t >> 6, lane = t & 63;
    int l15 = lane & 15, l4 = lane >> 4;
    int mh = wid * 3;
    int pos = l15;

    bf16x8 bfr[16];
    const char* xsb = reinterpret_cast<const char*>(xs) + pos * 1024;
    int swz = (pos & 7) << 4;
#pragma unroll
    for (int kk = 0; kk < 16; ++kk)
        bfr[kk] = *reinterpret_cast<const bf16x8*>(xsb + ((kk * 64 + l4 * 16) ^ swz));

    f32x4 acc[3];
#pragma unroll
    for (int i = 0; i < 3; ++i) acc[i] = (f32x4){0.f, 0.f, 0.f, 0.f};

#pragma unroll
    for (int i = 0; i < 3; ++i) {
        const unsigned short* wrow =
            Wqkv + ((size_t)(mh + i) * 16 + l15) * 512 + l4 * 8;
#pragma unroll
        for (int kk = 0; kk < 16; ++kk) {
            bf16x8 af = *reinterpret_cast<const bf16x8*>(wrow + kk * 32);
            acc[i] = __builtin_amdgcn_mfma_f32_16x16x32_bf16(af, bfr[kk], acc[i], 0, 0, 0);
        }
    }

#pragma unroll
    for (int i = 0; i < 3; ++i) {
        int mf = mh + i;
        int br = mf >> 2;
        const float* bb  = br == 0 ? bq  : br == 1 ? bk  : bv;
        const float* gg  = br == 0 ? gq  : br == 1 ? gk  : gv;
        const float* bt  = br == 0 ? btq : br == 1 ? btk : btv;
        const float* mm  = br == 0 ? mq  : br == 1 ? mk  : mv;
        const float* vvp = br == 0 ? vq  : br == 1 ? vk  : vv;
        float*       op  = br == 0 ? outq : br == 1 ? outk : outv;
        int cb = (mf & 3) * 16 + l4 * 4;
#pragma unroll
        for (int r = 0; r < 4; ++r) {
            int c = cb + r;
            float s = gg[c] * rsqrtf(vvp[c] + EPSBN);
            float val = (acc[i][r] + bb[c] - mm[c]) * s + bt[c];
            op[((size_t)(n * CC + c)) * DHW + p0 + pos] = fmaxf(val, 0.f);
        }
    }
}

// ---------------------------------------------------------------------------
// attention (merged): blocks [0,1024) = spatial patt; [1024,1152) = datt.
// (unchanged)
// ---------------------------------------------------------------------------
__global__ __launch_bounds__(256) void att_kernel(
    const float* __restrict__ q, const float* __restrict__ k,
    const float* __restrict__ v,
    unsigned short* __restrict__ Pp, unsigned short* __restrict__ Dp)
{
    __shared__ float sk[256], sq[256], sw[256], red[4];
    int t = threadIdx.x;
    int bid = blockIdx.x;

    if (bid < 1024) {
        int n = bid >> 9, c = (bid >> 3) & 63, d = bid & 7;
        size_t base = (size_t)bid * HW;
        float kt = k[base + t];
        float qt = q[base + t];
        float vt = v[base + t];
        sk[t] = kt;
        sq[t] = qt;

        float m = kt;
#pragma unroll
        for (int off = 32; off >= 1; off >>= 1)
            m = fmaxf(m, __shfl_xor(m, off));
        if ((t & 63) == 0) red[t >> 6] = m;
        __syncthreads();
        float kmax = fmaxf(fmaxf(red[0], red[1]), fmaxf(red[2], red[3]));

        float qkm = qt * kmax;
        float d0 = 0.f, d1 = 0.f, d2 = 0.f, d3 = 0.f;
        for (int j = 0; j < 256; j += 4) {
            d0 += __expf(fmaf(qt, sk[j + 0], -qkm));
            d1 += __expf(fmaf(qt, sk[j + 1], -qkm));
            d2 += __expf(fmaf(qt, sk[j + 2], -qkm));
            d3 += __expf(fmaf(qt, sk[j + 3], -qkm));
        }
        float den = (d0 + d1) + (d2 + d3);
        sw[t] = vt / den;
        __syncthreads();

        float kjm = kt - kmax;
        float o0 = 0.f, o1 = 0.f, o2 = 0.f, o3 = 0.f;
        for (int i = 0; i < 256; i += 4) {
            o0 += sw[i + 0] * __expf(sq[i + 0] * kjm);
            o1 += sw[i + 1] * __expf(sq[i + 1] * kjm);
            o2 += sw[i + 2] * __expf(sq[i + 2] * kjm);
            o3 += sw[i + 3] * __expf(sq[i + 3] * kjm);
        }
        float o = (o0 + o1) + (o2 + o3);

        int h = t >> 4, w = t & 15;
        size_t dst = ((((size_t)(n * 10 + d + 1) * 8 + (c >> 3)) * PG)
                      + (h + 1) * 18 + (w + 1)) * 8 + (c & 7);
        Pp[dst] = f2bf(o);
    } else {
        int g = (bid - 1024) * 256 + t;
        int nc = g >> 8, hw = g & 255;
        int n = nc >> 6, c = nc & 63;
        size_t base = (size_t)nc * DHW + hw;

        float qv[8], kv[8], vv_[8];
#pragma unroll
        for (int d = 0; d < 8; ++d) {
            qv[d]  = q[base + d * HW];
            kv[d]  = k[base + d * HW];
            vv_[d] = v[base + d * HW];
        }
        float kmax = 0.f;
#pragma unroll
        for (int d = 0; d < 8; ++d) kmax = fmaxf(kmax, kv[d]);

        float wgt[8];
#pragma unroll
        for (int i = 0; i < 8; ++i) {
            float den = 0.f, qkm = qv[i] * kmax;
#pragma unroll
            for (int j = 0; j < 8; ++j)
                den += __expf(fmaf(qv[i], kv[j], -qkm));
            wgt[i] = vv_[i] / den;
        }
        int h = hw >> 4, w = hw & 15;
#pragma unroll
        for (int j = 0; j < 8; ++j) {
            float o = 0.f, kjm = kv[j] - kmax;
#pragma unroll
            for (int i = 0; i < 8; ++i)
                o += wgt[i] * __expf(qv[i] * kjm);
            size_t dst = ((((size_t)(n * 10 + j + 1) * 8 + (c >> 3)) * PG)
                          + (h + 1) * 18 + (w + 1)) * 8 + (c & 7);
            Dp[dst] = f2bf(o);
        }
    }
}

// ---------------------------------------------------------------------------
// fused dual-branch MFMA conv + BN + ReLU + gama*(a+b) + x.
// grid = 512 = (xcd 8) x (ct 16) x (pg 2) x (slh 2): 2 blocks/CU, 8 waves/CU.
// pg-split: block owns 8 h-rows (10-row halo slab, 34.6 KB). Weights LDS-
// staged via global_load_lds, double-buffered 18.4 KB chunks, dense
// conflict-free layout. Input stage is async-split (reg-load early,
// LDS-write after barrier). LDS total 71.4 KB.
// ---------------------------------------------------------------------------
__global__ __launch_bounds__(256, 2) void conv_fused_kernel(
    const unsigned short* __restrict__ Pp, const unsigned short* __restrict__ Dp,
    const unsigned short* __restrict__ Wt,
    const float* __restrict__ bs, const float* __restrict__ gs,
    const float* __restrict__ bts, const float* __restrict__ ms,
    const float* __restrict__ vs,
    const float* __restrict__ bd, const float* __restrict__ gd,
    const float* __restrict__ btd, const float* __restrict__ md,
    const float* __restrict__ vd,
    const float* __restrict__ x, const float* __restrict__ gama,
    float* __restrict__ out)
{
    int bid = blockIdx.x;
    int xcd  = bid & 7;            // same-xcd blocks share a slice pair (L2)
    int rest = bid >> 3;           // 0..63
    int ct   = rest & 15;
    int pg   = (rest >> 4) & 1;
    int slh  = (rest >> 5) & 1;
    int sl   = xcd * 2 + slh;
    int n = sl >> 3, d = sl & 7;

    // input slab: [pl 12][10 rows][18 cols][8 ci] = 17280 shorts = 34560 B
    __shared__ __align__(16) unsigned short lds_in[12 * 1440];
    // weight double buffer: 2 x 9216 shorts = 36864 B (total 71424 B)
    __shared__ __align__(16) unsigned short lds_w[2][9216];

    int t = threadIdx.x;
    int wid = t >> 6, lane = t & 63;
    int l15 = lane & 15, l4 = lane >> 4;
    int hrow = wid * 2;            // wave covers 2 h-rows within pg

    f32x4 acc[2][2][2];   // [branch][mt][nt]
#pragma unroll
    for (int b = 0; b < 2; ++b)
#pragma unroll
        for (int mt = 0; mt < 2; ++mt)
#pragma unroll
            for (int nt = 0; nt < 2; ++nt)
                acc[b][mt][nt] = (f32x4){0.f, 0.f, 0.f, 0.f};

    uint4 streg[9];

#define STAGE_LOAD(p_) do {                                                   \
    const int hf_ = (p_) & 1;                                                 \
    const unsigned short* In_ = ((p_) >> 1) ? Dp : Pp;                        \
    _Pragma("unroll")                                                         \
    for (int i = 0; i < 9; ++i) {                                             \
        int idx = i * 256 + t;                                                \
        if (idx < 2160) {                                                     \
            int pl = idx / 180, rem = idx - pl * 180;                         \
            streg[i] = *(reinterpret_cast<const uint4*>(                      \
                In_ + ((size_t)((n * 10 + d + (pl >> 2)) * 8 + hf_ * 4        \
                                + (pl & 3))) * GPLN + pg * 1152) + rem);      \
        }                                                                     \
    }                                                                         \
} while (0)

#define STAGE_WRITE() do {                                                    \
    _Pragma("unroll")                                                         \
    for (int i = 0; i < 9; ++i) {                                             \
        int idx = i * 256 + t;                                                \
        if (idx < 2160)                                                       \
            reinterpret_cast<uint4*>(lds_in)[idx] = streg[i];                 \
    }                                                                         \
} while (0)

#define PREF_W(c_) do {                                                       \
    const int p_ = (c_) / 3, kd_ = (c_) % 3;                                  \
    const unsigned short* src_ = Wt + (size_t)(p_ >> 1) * WTSZ                \
        + (size_t)((ct * 2 + (p_ & 1)) * 3 + kd_) * 9216;                     \
    unsigned short* db_ = &lds_w[(c_) & 1][0];                                \
    for (int i = wid; i < 18; i += 4)                                         \
        __builtin_amdgcn_global_load_lds(                                     \
            (const u32_g*)(src_ + i * 512 + lane * 8),                        \
            (u32_l*)(db_ + i * 512), 16, 0, 0);                               \
} while (0)

#define COMPUTE(c_) do {                                                      \
    const int kd_ = (c_) % 3, br_ = (c_) / 6;                                 \
    const unsigned short* wb_ = &lds_w[(c_) & 1][0];                          \
    bf16x8 gg[4][3];                                                          \
    _Pragma("unroll")                                                         \
    for (int rr = 0; rr < 4; ++rr)                                            \
        _Pragma("unroll")                                                     \
        for (int kw = 0; kw < 3; ++kw)                                        \
            gg[rr][kw] = *reinterpret_cast<const bf16x8*>(                    \
                &lds_in[(kd_ * 4 + l4) * 1440                                 \
                        + ((hrow + rr) * 18 + l15 + kw) * 8]);                \
    _Pragma("unroll")                                                         \
    for (int kh = 0; kh < 3; ++kh)                                            \
        _Pragma("unroll")                                                     \
        for (int kw = 0; kw < 3; ++kw) {                                      \
            int tapk_ = kh * 3 + kw;                                          \
            bf16x8 af0 = *reinterpret_cast<const bf16x8*>(                    \
                &wb_[tapk_ * 1024 + l15 * 32 + l4 * 8]);                      \
            bf16x8 af1 = *reinterpret_cast<const bf16x8*>(                    \
                &wb_[tapk_ * 1024 + 512 + l15 * 32 + l4 * 8]);                \
            _Pragma("unroll")                                                 \
            for (int nt = 0; nt < 2; ++nt) {                                  \
                acc[br_][0][nt] = __builtin_amdgcn_mfma_f32_16x16x32_bf16(    \
                    af0, gg[nt + kh][kw], acc[br_][0][nt], 0, 0, 0);          \
                acc[br_][1][nt] = __builtin_amdgcn_mfma_f32_16x16x32_bf16(    \
                    af1, gg[nt + kh][kw], acc[br_][1][nt], 0, 0, 0);          \
            }                                                                 \
        }                                                                     \
} while (0)

    STAGE_LOAD(0);
    STAGE_WRITE();
    PREF_W(0);
    __syncthreads();

#pragma unroll
    for (int c = 0; c < 12; ++c) {
        if (c < 11) PREF_W(c + 1);
        const bool phase_end = (c % 3 == 2) && (c < 11);
        if (phase_end) STAGE_LOAD(c / 3 + 1);   // async: loads fly over MFMA
        COMPUTE(c);
        if (c < 11) {
            __syncthreads();                    // drains gload_lds + stage loads
            if (phase_end) {
                STAGE_WRITE();
                __syncthreads();
            }
        }
    }

#undef STAGE_LOAD
#undef STAGE_WRITE
#undef PREF_W
#undef COMPUTE

    // fused epilogue
    float gm = gama[0];
#pragma unroll
    for (int mt = 0; mt < 2; ++mt) {
#pragma unroll
        for (int r = 0; r < 4; ++r) {
            int co = ct * 32 + mt * 16 + l4 * 4 + r;
            float sS = gs[co] * rsqrtf(vs[co] + EPSBN);
            float oS = bs[co] - ms[co];
            float tS = bts[co];
            float sD = gd[co] * rsqrtf(vd[co] + EPSBN);
            float oD = bd[co] - md[co];
            float tD = btd[co];
#pragma unroll
            for (int nt = 0; nt < 2; ++nt) {
                int h = pg * 8 + hrow + nt;
                size_t oi = ((size_t)(n * 512 + co)) * 2048 + d * 256 + h * 16 + l15;
                float rp = fmaxf((acc[0][mt][nt][r] + oS) * sS + tS, 0.f);
                float rd = fmaxf((acc[1][mt][nt][r] + oD) * sD + tD, 0.f);
                out[oi] = gm * (rp + rd) + x[oi];
            }
        }
    }
}

// ---------------------------------------------------------------------------
extern "C" void kernel_launch(void* const* d_in, const int* in_sizes, int n_in,
                              void* d_out, int out_size, void* d_ws, size_t ws_size,
                              hipStream_t stream)
{
    const float* x    = (const float*)d_in[0];
    const float* gama = (const float*)d_in[1];
    const float* Wq  = (const float*)d_in[2];
    const float* bq  = (const float*)d_in[3];
    const float* gq  = (const float*)d_in[4];
    const float* btq = (const float*)d_in[5];
    const float* mq  = (const float*)d_in[6];
    const float* vq  = (const float*)d_in[7];
    const float* Wk  = (const float*)d_in[8];
    const float* bk  = (const float*)d_in[9];
    const float* gk  = (const float*)d_in[10];
    const float* btk = (const float*)d_in[11];
    const float* mk  = (const float*)d_in[12];
    const float* vk  = (const float*)d_in[13];
    const float* Wv  = (const float*)d_in[14];
    const float* bv  = (const float*)d_in[15];
    const float* gv  = (const float*)d_in[16];
    const float* btv = (const float*)d_in[17];
    const float* mv  = (const float*)d_in[18];
    const float* vv  = (const float*)d_in[19];
    const float* Ws  = (const float*)d_in[20];
    const float* bs  = (const float*)d_in[21];
    const float* gs  = (const float*)d_in[22];
    const float* bts = (const float*)d_in[23];
    const float* ms  = (const float*)d_in[24];
    const float* vs  = (const float*)d_in[25];
    const float* Wd  = (const float*)d_in[26];
    const float* bd  = (const float*)d_in[27];
    const float* gd  = (const float*)d_in[28];
    const float* btd = (const float*)d_in[29];
    const float* md  = (const float*)d_in[30];
    const float* vd  = (const float*)d_in[31];

    char* ws = (char*)d_ws;
    unsigned short* Pp   = (unsigned short*)ws;                 // 829440 B
    unsigned short* Dp   = Pp + PADSZ;                          // 829440 B
    unsigned short* Wt   = Dp + PADSZ;                          // 3538944 B
    unsigned short* Wqkv = Wt + 2 * WTSZ;                       // 196608 B
    float* q = (float*)(ws + 5394432);
    float* k = q + QSZ;
    float* v = k + QSZ;

    prep_kernel<<<1621, 256, 0, stream>>>(Ws, Wd, Wq, Wk, Wv,
                                          (uint4*)Pp, Wt, Wqkv);

    qkv_gemm_kernel<<<256, 256, 0, stream>>>(
        x, Wqkv,
        bq, gq, btq, mq, vq,
        bk, gk, btk, mk, vk,
        bv, gv, btv, mv, vv,
        q, k, v);

    att_kernel<<<1152, 256, 0, stream>>>(q, k, v, Pp, Dp);

    conv_fused_kernel<<<512, 256, 0, stream>>>(
        Pp, Dp, Wt,
        bs, gs, bts, ms, vs,
        bd, gd, btd, md, vd,
        x, gama, (float*)d_out);
}

// Round 9
// 69.725 us; speedup vs baseline: 1.4436x; 1.1191x over previous
//
#include <hip/hip_runtime.h>
#include <cmath>

#define EPSBN 1e-5f

namespace {
constexpr int C_IN = 512;
constexpr int CC   = 64;
constexpr int CD   = 8;
constexpr int HW   = 256;
constexpr int DHW  = CD * HW;        // 2048
constexpr int QSZ  = 2 * CC * DHW;   // 262144 floats per q/k/v buffer

// padded input layout for conv: [n 2][dp 10][g 8][row 18][col 18][cil 8] bf16
constexpr int PG    = 18 * 18;           // 324
constexpr int GPLN  = PG * 8;            // 2592 elems per (dp,g) plane
constexpr int PADSZ = 2 * 10 * 8 * GPLN; // 414720 elems per branch
// Wt layout: [branch][chunk 96][tapk 9][co 64][ci 16] bf16, chunk =
// ((cog*2+half)*3+kd)*2+cig  -> dense, conflict-free, gload_lds-linear.
constexpr int WTSZ  = 27 * 512 * 64;     // 884736 elems per branch
constexpr int PSTR  = 1448;              // padded LDS plane stride (shorts)

typedef __attribute__((ext_vector_type(8))) short bf16x8;
typedef __attribute__((ext_vector_type(4))) float f32x4;
typedef __attribute__((ext_vector_type(16))) float f32x16;

typedef unsigned int u32_g __attribute__((address_space(1)));
typedef unsigned int u32_l __attribute__((address_space(3)));

__device__ inline unsigned short f2bf(float f) {
    unsigned u = __float_as_uint(f);
    return (unsigned short)((u + 0x7fffu + ((u >> 16) & 1u)) >> 16);
}
}

// ---------------------------------------------------------------------------
// prep: [0,405) zero pads | [405,1429) weight relayout | [1429,1621) Wqkv |
//       [1621,1625) BN coefficient precompute (scale, offset) per (br, co)
// ---------------------------------------------------------------------------
__global__ __launch_bounds__(256) void prep_kernel(
    const float* __restrict__ Ws, const float* __restrict__ Wd,
    const float* __restrict__ Wq, const float* __restrict__ Wk,
    const float* __restrict__ Wv,
    const float* __restrict__ bs, const float* __restrict__ gs,
    const float* __restrict__ bts, const float* __restrict__ ms,
    const float* __restrict__ vs,
    const float* __restrict__ bd, const float* __restrict__ gd,
    const float* __restrict__ btd, const float* __restrict__ md,
    const float* __restrict__ vd,
    uint4* __restrict__ pads, unsigned short* __restrict__ Wt,
    unsigned short* __restrict__ Wqkv, float2* __restrict__ BNc)
{
    int bid = blockIdx.x;
    int t = threadIdx.x;
    if (bid < 405) {
        pads[bid * 256 + t] = make_uint4(0, 0, 0, 0);
    } else if (bid < 1429) {
        int b2 = bid - 405;
        int b  = b2 >> 9;
        int co = b2 & 511;
        const float* W = b ? Wd : Ws;
        int cog = co >> 6, co_l = co & 63;
        unsigned short* o = Wt + (size_t)b * WTSZ;
        for (int k = t; k < 27 * 64; k += 256) {
            int tap = k >> 6, ci = k & 63;
            int kd = tap / 9, tapk = tap - kd * 9;
            int half = ci >> 5, cl = ci & 31;
            int cig = cl >> 4, ci16 = cl & 15;
            float w = W[((size_t)co * 64 + ci) * 27 + tap];
            int chunk = ((cog * 2 + half) * 3 + kd) * 2 + cig;
            o[(size_t)chunk * 9216 + tapk * 1024 + co_l * 16 + ci16] = f2bf(w);
        }
    } else if (bid < 1621) {
        int co = bid - 1429;          // 0..191
        const float* W = co < 64 ? Wq : co < 128 ? Wk : Wv;
        int c = co & 63;
        for (int ci = t; ci < 512; ci += 256)
            Wqkv[(size_t)co * 512 + ci] = f2bf(W[(size_t)c * 512 + ci]);
    } else {
        int gid = (bid - 1621) * 256 + t;     // 0..1023
        if (gid < 1024) {
            int br = gid >> 9, co = gid & 511;
            float s, o;
            if (br == 0) {
                s = gs[co] * rsqrtf(vs[co] + EPSBN);
                o = (bs[co] - ms[co]) * s + bts[co];
            } else {
                s = gd[co] * rsqrtf(vd[co] + EPSBN);
                o = (bd[co] - md[co]) * s + btd[co];
            }
            BNc[gid] = make_float2(s, o);
        }
    }
}

// ---------------------------------------------------------------------------
// fused transpose + MFMA GEMM for q/k/v (+BN+ReLU). (unchanged)
// ---------------------------------------------------------------------------
__global__ __launch_bounds__(256) void qkv_gemm_kernel(
    const float* __restrict__ x, const unsigned short* __restrict__ Wqkv,
    const float* __restrict__ bq, const float* __restrict__ gq,
    const float* __restrict__ btq, const float* __restrict__ mq,
    const float* __restrict__ vq,
    const float* __restrict__ bk, const float* __restrict__ gk,
    const float* __restrict__ btk, const float* __restrict__ mk,
    const float* __restrict__ vk,
    const float* __restrict__ bv, const float* __restrict__ gv,
    const float* __restrict__ btv, const float* __restrict__ mv,
    const float* __restrict__ vv,
    float* __restrict__ outq, float* __restrict__ outk, float* __restrict__ outv)
{
    int bid = blockIdx.x;
    int n = bid >> 7, p0 = (bid & 127) * 16;

    __shared__ __align__(16) unsigned short xs[16 * 512];   // 16 KB
    int t = threadIdx.x;

    const float* xb = x + ((size_t)n * C_IN) * DHW + p0;
#pragma unroll
    for (int pass = 0; pass < 8; ++pass) {
        int idx = pass * 256 + t;          // 0..2047
        int ci = idx >> 2, pq = idx & 3;
        float4 v4 = *reinterpret_cast<const float4*>(xb + (size_t)ci * DHW + pq * 4);
        float arr[4] = {v4.x, v4.y, v4.z, v4.w};
#pragma unroll
        for (int u = 0; u < 4; ++u) {
            int pos = pq * 4 + u;
            int boff = pos * 1024 + ((ci * 2) ^ ((pos & 7) << 4));
            *reinterpret_cast<unsigned short*>(
                reinterpret_cast<char*>(xs) + boff) = f2bf(arr[u]);
        }
    }
    __syncthreads();

    int wid = t >> 6, lane = t & 63;
    int l15 = lane & 15, l4 = lane >> 4;
    int mh = wid * 3;
    int pos = l15;

    bf16x8 bfr[16];
    const char* xsb = reinterpret_cast<const char*>(xs) + pos * 1024;
    int swz = (pos & 7) << 4;
#pragma unroll
    for (int kk = 0; kk < 16; ++kk)
        bfr[kk] = *reinterpret_cast<const bf16x8*>(xsb + ((kk * 64 + l4 * 16) ^ swz));

    f32x4 acc[3];
#pragma unroll
    for (int i = 0; i < 3; ++i) acc[i] = (f32x4){0.f, 0.f, 0.f, 0.f};

#pragma unroll
    for (int i = 0; i < 3; ++i) {
        const unsigned short* wrow =
            Wqkv + ((size_t)(mh + i) * 16 + l15) * 512 + l4 * 8;
#pragma unroll
        for (int kk = 0; kk < 16; ++kk) {
            bf16x8 af = *reinterpret_cast<const bf16x8*>(wrow + kk * 32);
            acc[i] = __builtin_amdgcn_mfma_f32_16x16x32_bf16(af, bfr[kk], acc[i], 0, 0, 0);
        }
    }

#pragma unroll
    for (int i = 0; i < 3; ++i) {
        int mf = mh + i;
        int br = mf >> 2;
        const float* bb  = br == 0 ? bq  : br == 1 ? bk  : bv;
        const float* gg  = br == 0 ? gq  : br == 1 ? gk  : gv;
        const float* bt  = br == 0 ? btq : br == 1 ? btk : btv;
        const float* mm  = br == 0 ? mq  : br == 1 ? mk  : mv;
        const float* vvp = br == 0 ? vq  : br == 1 ? vk  : vv;
        float*       op  = br == 0 ? outq : br == 1 ? outk : outv;
        int cb = (mf & 3) * 16 + l4 * 4;
#pragma unroll
        for (int r = 0; r < 4; ++r) {
            int c = cb + r;
            float s = gg[c] * rsqrtf(vvp[c] + EPSBN);
            float val = (acc[i][r] + bb[c] - mm[c]) * s + bt[c];
            op[((size_t)(n * CC + c)) * DHW + p0 + pos] = fmaxf(val, 0.f);
        }
    }
}

// ---------------------------------------------------------------------------
// attention (merged): blocks [0,1024) = spatial patt; [1024,1152) = datt.
// (unchanged)
// ---------------------------------------------------------------------------
__global__ __launch_bounds__(256) void att_kernel(
    const float* __restrict__ q, const float* __restrict__ k,
    const float* __restrict__ v,
    unsigned short* __restrict__ Pp, unsigned short* __restrict__ Dp)
{
    __shared__ float sk[256], sq[256], sw[256], red[4];
    int t = threadIdx.x;
    int bid = blockIdx.x;

    if (bid < 1024) {
        int n = bid >> 9, c = (bid >> 3) & 63, d = bid & 7;
        size_t base = (size_t)bid * HW;
        float kt = k[base + t];
        float qt = q[base + t];
        float vt = v[base + t];
        sk[t] = kt;
        sq[t] = qt;

        float m = kt;
#pragma unroll
        for (int off = 32; off >= 1; off >>= 1)
            m = fmaxf(m, __shfl_xor(m, off));
        if ((t & 63) == 0) red[t >> 6] = m;
        __syncthreads();
        float kmax = fmaxf(fmaxf(red[0], red[1]), fmaxf(red[2], red[3]));

        float qkm = qt * kmax;
        float d0 = 0.f, d1 = 0.f, d2 = 0.f, d3 = 0.f;
        for (int j = 0; j < 256; j += 4) {
            d0 += __expf(fmaf(qt, sk[j + 0], -qkm));
            d1 += __expf(fmaf(qt, sk[j + 1], -qkm));
            d2 += __expf(fmaf(qt, sk[j + 2], -qkm));
            d3 += __expf(fmaf(qt, sk[j + 3], -qkm));
        }
        float den = (d0 + d1) + (d2 + d3);
        sw[t] = vt / den;
        __syncthreads();

        float kjm = kt - kmax;
        float o0 = 0.f, o1 = 0.f, o2 = 0.f, o3 = 0.f;
        for (int i = 0; i < 256; i += 4) {
            o0 += sw[i + 0] * __expf(sq[i + 0] * kjm);
            o1 += sw[i + 1] * __expf(sq[i + 1] * kjm);
            o2 += sw[i + 2] * __expf(sq[i + 2] * kjm);
            o3 += sw[i + 3] * __expf(sq[i + 3] * kjm);
        }
        float o = (o0 + o1) + (o2 + o3);

        int h = t >> 4, w = t & 15;
        size_t dst = ((((size_t)(n * 10 + d + 1) * 8 + (c >> 3)) * PG)
                      + (h + 1) * 18 + (w + 1)) * 8 + (c & 7);
        Pp[dst] = f2bf(o);
    } else {
        int g = (bid - 1024) * 256 + t;
        int nc = g >> 8, hw = g & 255;
        int n = nc >> 6, c = nc & 63;
        size_t base = (size_t)nc * DHW + hw;

        float qv[8], kv[8], vv_[8];
#pragma unroll
        for (int d = 0; d < 8; ++d) {
            qv[d]  = q[base + d * HW];
            kv[d]  = k[base + d * HW];
            vv_[d] = v[base + d * HW];
        }
        float kmax = 0.f;
#pragma unroll
        for (int d = 0; d < 8; ++d) kmax = fmaxf(kmax, kv[d]);

        float wgt[8];
#pragma unroll
        for (int i = 0; i < 8; ++i) {
            float den = 0.f, qkm = qv[i] * kmax;
#pragma unroll
            for (int j = 0; j < 8; ++j)
                den += __expf(fmaf(qv[i], kv[j], -qkm));
            wgt[i] = vv_[i] / den;
        }
        int h = hw >> 4, w = hw & 15;
#pragma unroll
        for (int j = 0; j < 8; ++j) {
            float o = 0.f, kjm = kv[j] - kmax;
#pragma unroll
            for (int i = 0; i < 8; ++i)
                o += wgt[i] * __expf(qv[i] * kjm);
            size_t dst = ((((size_t)(n * 10 + j + 1) * 8 + (c >> 3)) * PG)
                          + (h + 1) * 18 + (w + 1)) * 8 + (c & 7);
            Dp[dst] = f2bf(o);
        }
    }
}

// ---------------------------------------------------------------------------
// fused dual-branch conv, 32x32x16 MFMA.
// grid = 256 = (cog 8 = XCD) x (pgb 2) x (sl 16); block 256 thr = 4 waves =
// (ph 2 pos-halves) x (br 2). Wave: 64 co (mrep 2) x 64 pos (2 pos-tiles),
// acc = 2x2 f32x16. Weights dbuf'd 36.9 KB chunks via global_load_lds;
// input slabs (both br, PSTR-padded) resident; half-1 restage via T14.
// Epilogue: S-waves -> LDS -> D-waves combine + store.
// ---------------------------------------------------------------------------
__global__ __launch_bounds__(256, 1) void conv_fused_kernel(
    const unsigned short* __restrict__ Pp, const unsigned short* __restrict__ Dp,
    const unsigned short* __restrict__ Wt,
    const float2* __restrict__ BNc,
    const float* __restrict__ x, const float* __restrict__ gama,
    float* __restrict__ out)
{
    int bid = blockIdx.x;
    int cog = bid & 7;             // == XCD (round-robin) -> weights L2-local
    int pgb = (bid >> 3) & 1;
    int sl  = bid >> 4;
    int n = sl >> 3, d = sl & 7;

    __shared__ __align__(16) unsigned short lds_in[2 * 12 * PSTR]; // 69504 B
    __shared__ __align__(16) unsigned short lds_w[2 * 18432];      // 73728 B

    int t = threadIdx.x;
    int wid = t >> 6, lane = t & 63;
    int ph = wid & 1, br = wid >> 1;
    int col  = lane & 31;          // pos / co within 32-tile
    int wcol = lane & 15;
    int hl   = (lane >> 4) & 1;
    int ks   = lane >> 5;          // k-slot (ci granule within ci16)

    f32x16 acc[2][2];
#pragma unroll
    for (int m = 0; m < 2; ++m)
#pragma unroll
        for (int p = 0; p < 2; ++p)
#pragma unroll
            for (int r = 0; r < 16; ++r)
                acc[m][p][r] = 0.f;

#define DMAW(c_) do {                                                         \
    const int ch_ = (((cog * 2 + ((c_) / 6)) * 3 + (((c_) % 6) >> 1)) * 2     \
                     + ((c_) & 1)) * 9216;                                    \
    _Pragma("unroll")                                                         \
    for (int j = 0; j < 9; ++j) {                                             \
        int base = j * 2048 + wid * 512;                                      \
        const unsigned short* s0 = (base < 9216)                              \
            ? (Wt + ch_ + base)                                               \
            : (Wt + WTSZ + ch_ + (base - 9216));                              \
        __builtin_amdgcn_global_load_lds(                                     \
            (const u32_g*)(s0 + lane * 8),                                    \
            (u32_l*)(lds_w + ((c_) & 1) * 18432 + base), 16, 0, 0);           \
    }                                                                         \
} while (0)

#define COMPUTE(c_) do {                                                      \
    const int kd_ = ((c_) % 6) >> 1, cig_ = (c_) & 1;                         \
    const unsigned short* wb_ = lds_w + ((c_) & 1) * 18432 + br * 9216;       \
    const unsigned short* bp_ = lds_in + br * (12 * PSTR)                     \
                                + (kd_ * 4 + cig_ * 2 + ks) * PSTR;           \
    _Pragma("unroll")                                                         \
    for (int tapk = 0; tapk < 9; ++tapk) {                                    \
        const int kh_ = tapk / 3, kw_ = tapk % 3;                             \
        bf16x8 a0 = *(const bf16x8*)(wb_ + tapk * 1024 + col * 16 + ks * 8);  \
        bf16x8 a1 = *(const bf16x8*)(wb_ + tapk * 1024 + 512 + col * 16       \
                                     + ks * 8);                               \
        bf16x8 b0 = *(const bf16x8*)(bp_ + ((ph * 4 + hl + kh_) * 18          \
                                     + wcol + kw_) * 8);                      \
        bf16x8 b1 = *(const bf16x8*)(bp_ + ((ph * 4 + 2 + hl + kh_) * 18      \
                                     + wcol + kw_) * 8);                      \
        acc[0][0] = __builtin_amdgcn_mfma_f32_32x32x16_bf16(a0, b0,           \
                        acc[0][0], 0, 0, 0);                                  \
        acc[0][1] = __builtin_amdgcn_mfma_f32_32x32x16_bf16(a0, b1,           \
                        acc[0][1], 0, 0, 0);                                  \
        acc[1][0] = __builtin_amdgcn_mfma_f32_32x32x16_bf16(a1, b0,           \
                        acc[1][0], 0, 0, 0);                                  \
        acc[1][1] = __builtin_amdgcn_mfma_f32_32x32x16_bf16(a1, b1,           \
                        acc[1][1], 0, 0, 0);                                  \
    }                                                                         \
} while (0)

    // ---- initial input stage (half 0, both branches) ----
#pragma unroll
    for (int i = 0; i < 17; ++i) {
        int idx = i * 256 + t;
        if (idx < 4320) {
            int b2 = idx >= 2160 ? 1 : 0;
            int sub = idx - b2 * 2160;
            int pl = sub / 180, rem = sub - pl * 180;
            const uint4* s = reinterpret_cast<const uint4*>(
                (b2 ? Dp : Pp)
                + (size_t)((n * 10 + d + (pl >> 2)) * 8 + (pl & 3)) * GPLN
                + pgb * 1152) + rem;
            reinterpret_cast<uint4*>(lds_in)[b2 * 2172 + pl * 181 + rem] = *s;
        }
    }
    DMAW(0);
    __syncthreads();

    uint4 streg[17];

#pragma unroll
    for (int c = 0; c < 12; ++c) {
        if (c < 11) DMAW(c + 1);
        if (c == 5) {
            // T14: issue half-1 input loads; they fly over COMPUTE(5)
#pragma unroll
            for (int i = 0; i < 17; ++i) {
                int idx = i * 256 + t;
                if (idx < 4320) {
                    int b2 = idx >= 2160 ? 1 : 0;
                    int sub = idx - b2 * 2160;
                    int pl = sub / 180, rem = sub - pl * 180;
                    streg[i] = *(reinterpret_cast<const uint4*>(
                        (b2 ? Dp : Pp)
                        + (size_t)((n * 10 + d + (pl >> 2)) * 8 + 4
                                   + (pl & 3)) * GPLN + pgb * 1152) + rem);
                }
            }
        }
        COMPUTE(c);
        __syncthreads();
        if (c == 5) {
#pragma unroll
            for (int i = 0; i < 17; ++i) {
                int idx = i * 256 + t;
                if (idx < 4320) {
                    int b2 = idx >= 2160 ? 1 : 0;
                    int sub = idx - b2 * 2160;
                    int pl = sub / 180, rem = sub - pl * 180;
                    reinterpret_cast<uint4*>(lds_in)[b2 * 2172 + pl * 181 + rem]
                        = streg[i];
                }
            }
            __syncthreads();
        }
    }

#undef DMAW
#undef COMPUTE

    // ---- fused epilogue: S-waves -> LDS, D-waves combine + store ----
    float gm = gama[0];
    float* ep = reinterpret_cast<float*>(lds_w);

    if (br == 0) {
#pragma unroll
        for (int m = 0; m < 2; ++m)
#pragma unroll
            for (int p = 0; p < 2; ++p)
#pragma unroll
                for (int r = 0; r < 16; ++r) {
                    int row = (r & 3) + 8 * (r >> 2) + 4 * ks;
                    float2 c2 = BNc[cog * 64 + m * 32 + row];
                    float v = fmaxf(acc[m][p][r] * c2.x + c2.y, 0.f);
                    ep[ph * 4096 + (m * 32 + row) * 64 + p * 32 + col] = v;
                }
    }
    __syncthreads();
    if (br == 1) {
#pragma unroll
        for (int m = 0; m < 2; ++m)
#pragma unroll
            for (int p = 0; p < 2; ++p)
#pragma unroll
                for (int r = 0; r < 16; ++r) {
                    int row = (r & 3) + 8 * (r >> 2) + 4 * ks;
                    int co = cog * 64 + m * 32 + row;
                    float2 c2 = BNc[512 + co];
                    float rd = fmaxf(acc[m][p][r] * c2.x + c2.y, 0.f);
                    float rp = ep[ph * 4096 + (m * 32 + row) * 64 + p * 32 + col];
                    int pos = pgb * 128 + ph * 64 + p * 32 + col;
                    size_t oi = ((size_t)(n * 512 + co)) * 2048 + d * 256 + pos;
                    out[oi] = gm * (rp + rd) + x[oi];
                }
    }
}

// ---------------------------------------------------------------------------
extern "C" void kernel_launch(void* const* d_in, const int* in_sizes, int n_in,
                              void* d_out, int out_size, void* d_ws, size_t ws_size,
                              hipStream_t stream)
{
    const float* x    = (const float*)d_in[0];
    const float* gama = (const float*)d_in[1];
    const float* Wq  = (const float*)d_in[2];
    const float* bq  = (const float*)d_in[3];
    const float* gq  = (const float*)d_in[4];
    const float* btq = (const float*)d_in[5];
    const float* mq  = (const float*)d_in[6];
    const float* vq  = (const float*)d_in[7];
    const float* Wk  = (const float*)d_in[8];
    const float* bk  = (const float*)d_in[9];
    const float* gk  = (const float*)d_in[10];
    const float* btk = (const float*)d_in[11];
    const float* mk  = (const float*)d_in[12];
    const float* vk  = (const float*)d_in[13];
    const float* Wv  = (const float*)d_in[14];
    const float* bv  = (const float*)d_in[15];
    const float* gv  = (const float*)d_in[16];
    const float* btv = (const float*)d_in[17];
    const float* mv  = (const float*)d_in[18];
    const float* vv  = (const float*)d_in[19];
    const float* Ws  = (const float*)d_in[20];
    const float* bs  = (const float*)d_in[21];
    const float* gs  = (const float*)d_in[22];
    const float* bts = (const float*)d_in[23];
    const float* ms  = (const float*)d_in[24];
    const float* vs  = (const float*)d_in[25];
    const float* Wd  = (const float*)d_in[26];
    const float* bd  = (const float*)d_in[27];
    const float* gd  = (const float*)d_in[28];
    const float* btd = (const float*)d_in[29];
    const float* md  = (const float*)d_in[30];
    const float* vd  = (const float*)d_in[31];

    char* ws = (char*)d_ws;
    unsigned short* Pp   = (unsigned short*)ws;                 // 829440 B
    unsigned short* Dp   = Pp + PADSZ;                          // 829440 B
    unsigned short* Wt   = Dp + PADSZ;                          // 3538944 B
    unsigned short* Wqkv = Wt + 2 * WTSZ;                       // 196608 B
    float* q = (float*)(ws + 5394432);
    float* k = q + QSZ;
    float* v = k + QSZ;
    float2* BNc = (float2*)(ws + 5394432 + 3 * 1048576);        // 8192 B

    prep_kernel<<<1625, 256, 0, stream>>>(
        Ws, Wd, Wq, Wk, Wv,
        bs, gs, bts, ms, vs,
        bd, gd, btd, md, vd,
        (uint4*)Pp, Wt, Wqkv, BNc);

    qkv_gemm_kernel<<<256, 256, 0, stream>>>(
        x, Wqkv,
        bq, gq, btq, mq, vq,
        bk, gk, btk, mk, vk,
        bv, gv, btv, mv, vv,
        q, k, v);

    att_kernel<<<1152, 256, 0, stream>>>(q, k, v, Pp, Dp);

    conv_fused_kernel<<<256, 256, 0, stream>>>(
        Pp, Dp, Wt, BNc,
        x, gama, (float*)d_out);
}

// Round 10
// 65.020 us; speedup vs baseline: 1.5481x; 1.0724x over previous
//
#include <hip/hip_runtime.h>
#include <cmath>

#define EPSBN 1e-5f

namespace {
constexpr int C_IN = 512;
constexpr int CC   = 64;
constexpr int CD   = 8;
constexpr int HW   = 256;
constexpr int DHW  = CD * HW;        // 2048
constexpr int QSZ  = 2 * CC * DHW;   // 262144 floats per q/k/v buffer

// padded input layout for conv: [n 2][dp 10][g 8][row 18][col 18][cil 8] bf16
constexpr int PG    = 18 * 18;           // 324
constexpr int GPLN  = PG * 8;            // 2592 elems per (dp,g) plane
constexpr int PADSZ = 2 * 10 * 8 * GPLN; // 414720 elems per branch
// Wt layout: [branch][chunk 96][tapk 9][coh 2][pg 64][ci8] bf16 where the
// 16B granule index pg = (2*co + ks) ^ (co & 7)  (bank-floor swizzle; the
// same XOR is applied on the LDS read side; DMA copies stay linear).
constexpr int WTSZ  = 27 * 512 * 64;     // 884736 elems per branch

typedef __attribute__((ext_vector_type(8))) short bf16x8;
typedef __attribute__((ext_vector_type(4))) float f32x4;
typedef __attribute__((ext_vector_type(16))) float f32x16;

typedef unsigned int u32_g __attribute__((address_space(1)));
typedef unsigned int u32_l __attribute__((address_space(3)));

__device__ inline unsigned short f2bf(float f) {
    unsigned u = __float_as_uint(f);
    return (unsigned short)((u + 0x7fffu + ((u >> 16) & 1u)) >> 16);
}
}

// ---------------------------------------------------------------------------
// prep: [0,405) zero pads | [405,1429) weight relayout+swizzle |
//       [1429,1621) Wqkv | [1621,1625) BN coefficient precompute
// ---------------------------------------------------------------------------
__global__ __launch_bounds__(256) void prep_kernel(
    const float* __restrict__ Ws, const float* __restrict__ Wd,
    const float* __restrict__ Wq, const float* __restrict__ Wk,
    const float* __restrict__ Wv,
    const float* __restrict__ bs, const float* __restrict__ gs,
    const float* __restrict__ bts, const float* __restrict__ ms,
    const float* __restrict__ vs,
    const float* __restrict__ bd, const float* __restrict__ gd,
    const float* __restrict__ btd, const float* __restrict__ md,
    const float* __restrict__ vd,
    uint4* __restrict__ pads, unsigned short* __restrict__ Wt,
    unsigned short* __restrict__ Wqkv, float2* __restrict__ BNc)
{
    int bid = blockIdx.x;
    int t = threadIdx.x;
    if (bid < 405) {
        pads[bid * 256 + t] = make_uint4(0, 0, 0, 0);
    } else if (bid < 1429) {
        int b2 = bid - 405;
        int b  = b2 >> 9;
        int co = b2 & 511;
        const float* W = b ? Wd : Ws;
        int cog = co >> 6, co_l = co & 63;
        int r  = co_l & 31, hi = co_l >> 5;
        unsigned short* o = Wt + (size_t)b * WTSZ;
        for (int k = t; k < 27 * 64; k += 256) {
            int tap = k >> 6, ci = k & 63;
            int kd = tap / 9, tapk = tap - kd * 9;
            int half = ci >> 5, cl = ci & 31;
            int cig = cl >> 4, ci16 = cl & 15;
            int ks = ci16 >> 3;
            float w = W[((size_t)co * 64 + ci) * 27 + tap];
            int chunk = ((cog * 2 + half) * 3 + kd) * 2 + cig;
            int pg = (r * 2 + ks) ^ (r & 7);                 // bank swizzle
            o[(size_t)chunk * 9216 + tapk * 1024 + hi * 512
              + pg * 8 + (ci16 & 7)] = f2bf(w);
        }
    } else if (bid < 1621) {
        int co = bid - 1429;          // 0..191
        const float* W = co < 64 ? Wq : co < 128 ? Wk : Wv;
        int c = co & 63;
        for (int ci = t; ci < 512; ci += 256)
            Wqkv[(size_t)co * 512 + ci] = f2bf(W[(size_t)c * 512 + ci]);
    } else {
        int gid = (bid - 1621) * 256 + t;     // 0..1023
        if (gid < 1024) {
            int br = gid >> 9, co = gid & 511;
            float s, o;
            if (br == 0) {
                s = gs[co] * rsqrtf(vs[co] + EPSBN);
                o = (bs[co] - ms[co]) * s + bts[co];
            } else {
                s = gd[co] * rsqrtf(vd[co] + EPSBN);
                o = (bd[co] - md[co]) * s + btd[co];
            }
            BNc[gid] = make_float2(s, o);
        }
    }
}

// ---------------------------------------------------------------------------
// fused transpose + MFMA GEMM for q/k/v (+BN+ReLU). (unchanged)
// ---------------------------------------------------------------------------
__global__ __launch_bounds__(256) void qkv_gemm_kernel(
    const float* __restrict__ x, const unsigned short* __restrict__ Wqkv,
    const float* __restrict__ bq, const float* __restrict__ gq,
    const float* __restrict__ btq, const float* __restrict__ mq,
    const float* __restrict__ vq,
    const float* __restrict__ bk, const float* __restrict__ gk,
    const float* __restrict__ btk, const float* __restrict__ mk,
    const float* __restrict__ vk,
    const float* __restrict__ bv, const float* __restrict__ gv,
    const float* __restrict__ btv, const float* __restrict__ mv,
    const float* __restrict__ vv,
    float* __restrict__ outq, float* __restrict__ outk, float* __restrict__ outv)
{
    int bid = blockIdx.x;
    int n = bid >> 7, p0 = (bid & 127) * 16;

    __shared__ __align__(16) unsigned short xs[16 * 512];   // 16 KB
    int t = threadIdx.x;

    const float* xb = x + ((size_t)n * C_IN) * DHW + p0;
#pragma unroll
    for (int pass = 0; pass < 8; ++pass) {
        int idx = pass * 256 + t;          // 0..2047
        int ci = idx >> 2, pq = idx & 3;
        float4 v4 = *reinterpret_cast<const float4*>(xb + (size_t)ci * DHW + pq * 4);
        float arr[4] = {v4.x, v4.y, v4.z, v4.w};
#pragma unroll
        for (int u = 0; u < 4; ++u) {
            int pos = pq * 4 + u;
            int boff = pos * 1024 + ((ci * 2) ^ ((pos & 7) << 4));
            *reinterpret_cast<unsigned short*>(
                reinterpret_cast<char*>(xs) + boff) = f2bf(arr[u]);
        }
    }
    __syncthreads();

    int wid = t >> 6, lane = t & 63;
    int l15 = lane & 15, l4 = lane >> 4;
    int mh = wid * 3;
    int pos = l15;

    bf16x8 bfr[16];
    const char* xsb = reinterpret_cast<const char*>(xs) + pos * 1024;
    int swz = (pos & 7) << 4;
#pragma unroll
    for (int kk = 0; kk < 16; ++kk)
        bfr[kk] = *reinterpret_cast<const bf16x8*>(xsb + ((kk * 64 + l4 * 16) ^ swz));

    f32x4 acc[3];
#pragma unroll
    for (int i = 0; i < 3; ++i) acc[i] = (f32x4){0.f, 0.f, 0.f, 0.f};

#pragma unroll
    for (int i = 0; i < 3; ++i) {
        const unsigned short* wrow =
            Wqkv + ((size_t)(mh + i) * 16 + l15) * 512 + l4 * 8;
#pragma unroll
        for (int kk = 0; kk < 16; ++kk) {
            bf16x8 af = *reinterpret_cast<const bf16x8*>(wrow + kk * 32);
            acc[i] = __builtin_amdgcn_mfma_f32_16x16x32_bf16(af, bfr[kk], acc[i], 0, 0, 0);
        }
    }

#pragma unroll
    for (int i = 0; i < 3; ++i) {
        int mf = mh + i;
        int br = mf >> 2;
        const float* bb  = br == 0 ? bq  : br == 1 ? bk  : bv;
        const float* gg  = br == 0 ? gq  : br == 1 ? gk  : gv;
        const float* bt  = br == 0 ? btq : br == 1 ? btk : btv;
        const float* mm  = br == 0 ? mq  : br == 1 ? mk  : mv;
        const float* vvp = br == 0 ? vq  : br == 1 ? vk  : vv;
        float*       op  = br == 0 ? outq : br == 1 ? outk : outv;
        int cb = (mf & 3) * 16 + l4 * 4;
#pragma unroll
        for (int r = 0; r < 4; ++r) {
            int c = cb + r;
            float s = gg[c] * rsqrtf(vvp[c] + EPSBN);
            float val = (acc[i][r] + bb[c] - mm[c]) * s + bt[c];
            op[((size_t)(n * CC + c)) * DHW + p0 + pos] = fmaxf(val, 0.f);
        }
    }
}

// ---------------------------------------------------------------------------
// attention (merged): blocks [0,1024) = spatial patt; [1024,1152) = datt.
// (unchanged)
// ---------------------------------------------------------------------------
__global__ __launch_bounds__(256) void att_kernel(
    const float* __restrict__ q, const float* __restrict__ k,
    const float* __restrict__ v,
    unsigned short* __restrict__ Pp, unsigned short* __restrict__ Dp)
{
    __shared__ float sk[256], sq[256], sw[256], red[4];
    int t = threadIdx.x;
    int bid = blockIdx.x;

    if (bid < 1024) {
        int n = bid >> 9, c = (bid >> 3) & 63, d = bid & 7;
        size_t base = (size_t)bid * HW;
        float kt = k[base + t];
        float qt = q[base + t];
        float vt = v[base + t];
        sk[t] = kt;
        sq[t] = qt;

        float m = kt;
#pragma unroll
        for (int off = 32; off >= 1; off >>= 1)
            m = fmaxf(m, __shfl_xor(m, off));
        if ((t & 63) == 0) red[t >> 6] = m;
        __syncthreads();
        float kmax = fmaxf(fmaxf(red[0], red[1]), fmaxf(red[2], red[3]));

        float qkm = qt * kmax;
        float d0 = 0.f, d1 = 0.f, d2 = 0.f, d3 = 0.f;
        for (int j = 0; j < 256; j += 4) {
            d0 += __expf(fmaf(qt, sk[j + 0], -qkm));
            d1 += __expf(fmaf(qt, sk[j + 1], -qkm));
            d2 += __expf(fmaf(qt, sk[j + 2], -qkm));
            d3 += __expf(fmaf(qt, sk[j + 3], -qkm));
        }
        float den = (d0 + d1) + (d2 + d3);
        sw[t] = vt / den;
        __syncthreads();

        float kjm = kt - kmax;
        float o0 = 0.f, o1 = 0.f, o2 = 0.f, o3 = 0.f;
        for (int i = 0; i < 256; i += 4) {
            o0 += sw[i + 0] * __expf(sq[i + 0] * kjm);
            o1 += sw[i + 1] * __expf(sq[i + 1] * kjm);
            o2 += sw[i + 2] * __expf(sq[i + 2] * kjm);
            o3 += sw[i + 3] * __expf(sq[i + 3] * kjm);
        }
        float o = (o0 + o1) + (o2 + o3);

        int h = t >> 4, w = t & 15;
        size_t dst = ((((size_t)(n * 10 + d + 1) * 8 + (c >> 3)) * PG)
                      + (h + 1) * 18 + (w + 1)) * 8 + (c & 7);
        Pp[dst] = f2bf(o);
    } else {
        int g = (bid - 1024) * 256 + t;
        int nc = g >> 8, hw = g & 255;
        int n = nc >> 6, c = nc & 63;
        size_t base = (size_t)nc * DHW + hw;

        float qv[8], kv[8], vv_[8];
#pragma unroll
        for (int d = 0; d < 8; ++d) {
            qv[d]  = q[base + d * HW];
            kv[d]  = k[base + d * HW];
            vv_[d] = v[base + d * HW];
        }
        float kmax = 0.f;
#pragma unroll
        for (int d = 0; d < 8; ++d) kmax = fmaxf(kmax, kv[d]);

        float wgt[8];
#pragma unroll
        for (int i = 0; i < 8; ++i) {
            float den = 0.f, qkm = qv[i] * kmax;
#pragma unroll
            for (int j = 0; j < 8; ++j)
                den += __expf(fmaf(qv[i], kv[j], -qkm));
            wgt[i] = vv_[i] / den;
        }
        int h = hw >> 4, w = hw & 15;
#pragma unroll
        for (int j = 0; j < 8; ++j) {
            float o = 0.f, kjm = kv[j] - kmax;
#pragma unroll
            for (int i = 0; i < 8; ++i)
                o += wgt[i] * __expf(qv[i] * kjm);
            size_t dst = ((((size_t)(n * 10 + j + 1) * 8 + (c >> 3)) * PG)
                          + (h + 1) * 18 + (w + 1)) * 8 + (c & 7);
            Dp[dst] = f2bf(o);
        }
    }
}

// ---------------------------------------------------------------------------
// fused dual-branch conv, 32x32x16 MFMA.
// grid = 256 = (cog 8 = XCD) x (pgb 2) x (sl 16); block 256 thr = 4 waves =
// (ph 2 pos-halves) x (br 2). Wave: 64 co x 64 pos, acc = 2x2 f32x16.
// ALL staging via global_load_lds (no reg round-trip, no spill):
//   input slab: 24 planes x 1536 shorts (10 rows data + pad) = 73.7 KB,
//   weights: 2 x 18432-short double buffer = 73.7 KB. Total 147.5 KB.
// Weight granules pre-swizzled (prep) -> A-reads at LDS bank floor.
// ---------------------------------------------------------------------------
__global__ __launch_bounds__(256, 1) void conv_fused_kernel(
    const unsigned short* __restrict__ Pp, const unsigned short* __restrict__ Dp,
    const unsigned short* __restrict__ Wt,
    const float2* __restrict__ BNc,
    const float* __restrict__ x, const float* __restrict__ gama,
    float* __restrict__ out)
{
    int bid = blockIdx.x;
    int cog = bid & 7;             // == XCD (round-robin) -> weights L2-local
    int pgb = (bid >> 3) & 1;
    int sl  = bid >> 4;
    int n = sl >> 3, d = sl & 7;

    __shared__ __align__(16) unsigned short lds_in[24 * 1536];    // 73728 B
    __shared__ __align__(16) unsigned short lds_w[2 * 18432];     // 73728 B

    int t = threadIdx.x;
    int wid = t >> 6, lane = t & 63;
    int ph = wid & 1, br = wid >> 1;
    int col  = lane & 31;          // pos / co within 32-tile
    int wcol = lane & 15;
    int hl   = (lane >> 4) & 1;
    int ks   = lane >> 5;          // ci granule within ci16
    int gA   = ((col * 2 + ks) ^ (col & 7)) * 8;  // swizzled A granule offset

    f32x16 acc[2][2];
#pragma unroll
    for (int m = 0; m < 2; ++m)
#pragma unroll
        for (int p = 0; p < 2; ++p)
#pragma unroll
            for (int r = 0; r < 16; ++r)
                acc[m][p][r] = 0.f;

// input stage: 24 pieces (2 br x 12 planes) x 3 full gload_lds each.
// Source window = rows [pgb*8, pgb*8+10) of a g-plane (2880 B); the third
// instruction over-reads 192 B (stays in ws) into never-read LDS pad rows.
#define ISTAGE(hf_) do {                                                      \
    _Pragma("unroll")                                                         \
    for (int pc = 0; pc < 24; ++pc) {                                         \
        const unsigned short* sb = ((pc >= 12) ? Dp : Pp)                     \
            + ((size_t)((n * 10 + d + ((pc % 12) >> 2)) * 8 + (hf_) * 4       \
                        + ((pc % 12) & 3))) * GPLN + pgb * 1152;              \
        _Pragma("unroll")                                                     \
        for (int j = 0; j < 3; ++j) {                                         \
            if (((pc * 3 + j) & 3) == wid)                                    \
                __builtin_amdgcn_global_load_lds(                             \
                    (const u32_g*)(sb + j * 512 + lane * 8),                  \
                    (u32_l*)(lds_in + pc * 1536 + j * 512), 16, 0, 0);        \
        }                                                                     \
    }                                                                         \
} while (0)

#define DMAW(c_) do {                                                         \
    const int ch_ = (((cog * 2 + ((c_) / 6)) * 3 + (((c_) % 6) >> 1)) * 2     \
                     + ((c_) & 1)) * 9216;                                    \
    _Pragma("unroll")                                                         \
    for (int j = 0; j < 9; ++j) {                                             \
        int base = j * 2048 + wid * 512;                                      \
        const unsigned short* s0 = (base < 9216)                              \
            ? (Wt + ch_ + base)                                               \
            : (Wt + WTSZ + ch_ + (base - 9216));                              \
        __builtin_amdgcn_global_load_lds(                                     \
            (const u32_g*)(s0 + lane * 8),                                    \
            (u32_l*)(lds_w + ((c_) & 1) * 18432 + base), 16, 0, 0);           \
    }                                                                         \
} while (0)

#define COMPUTE(c_) do {                                                      \
    const int kd_ = ((c_) % 6) >> 1, cig_ = (c_) & 1;                         \
    const unsigned short* wb_ = lds_w + ((c_) & 1) * 18432 + br * 9216;       \
    const unsigned short* bp_ = lds_in + br * (12 * 1536)                     \
                                + (kd_ * 4 + cig_ * 2 + ks) * 1536;           \
    _Pragma("unroll")                                                         \
    for (int tapk = 0; tapk < 9; ++tapk) {                                    \
        const int kh_ = tapk / 3, kw_ = tapk % 3;                             \
        bf16x8 a0 = *(const bf16x8*)(wb_ + tapk * 1024 + gA);                 \
        bf16x8 a1 = *(const bf16x8*)(wb_ + tapk * 1024 + 512 + gA);           \
        bf16x8 b0 = *(const bf16x8*)(bp_ + ((ph * 4 + hl + kh_) * 18          \
                                     + wcol + kw_) * 8);                      \
        bf16x8 b1 = *(const bf16x8*)(bp_ + ((ph * 4 + 2 + hl + kh_) * 18      \
                                     + wcol + kw_) * 8);                      \
        acc[0][0] = __builtin_amdgcn_mfma_f32_32x32x16_bf16(a0, b0,           \
                        acc[0][0], 0, 0, 0);                                  \
        acc[0][1] = __builtin_amdgcn_mfma_f32_32x32x16_bf16(a0, b1,           \
                        acc[0][1], 0, 0, 0);                                  \
        acc[1][0] = __builtin_amdgcn_mfma_f32_32x32x16_bf16(a1, b0,           \
                        acc[1][0], 0, 0, 0);                                  \
        acc[1][1] = __builtin_amdgcn_mfma_f32_32x32x16_bf16(a1, b1,           \
                        acc[1][1], 0, 0, 0);                                  \
    }                                                                         \
} while (0)

    ISTAGE(0);
    DMAW(0);
    __syncthreads();

#pragma unroll
    for (int c = 0; c < 12; ++c) {
        if (c < 11) DMAW(c + 1);       // next chunk flies over COMPUTE(c)
        COMPUTE(c);
        __syncthreads();               // drains gload_lds queue
        if (c == 5) {                  // switch to ci-half 1
            ISTAGE(1);
            __syncthreads();
        }
    }

#undef ISTAGE
#undef DMAW
#undef COMPUTE

    // ---- fused epilogue: S-waves -> LDS, D-waves combine + store ----
    float gm = gama[0];
    float* ep = reinterpret_cast<float*>(lds_w);

    if (br == 0) {
#pragma unroll
        for (int m = 0; m < 2; ++m)
#pragma unroll
            for (int p = 0; p < 2; ++p)
#pragma unroll
                for (int r = 0; r < 16; ++r) {
                    int row = (r & 3) + 8 * (r >> 2) + 4 * ks;
                    float2 c2 = BNc[cog * 64 + m * 32 + row];
                    float v = fmaxf(acc[m][p][r] * c2.x + c2.y, 0.f);
                    ep[ph * 4096 + (m * 32 + row) * 64 + p * 32 + col] = v;
                }
    }
    __syncthreads();
    if (br == 1) {
#pragma unroll
        for (int m = 0; m < 2; ++m)
#pragma unroll
            for (int p = 0; p < 2; ++p)
#pragma unroll
                for (int r = 0; r < 16; ++r) {
                    int row = (r & 3) + 8 * (r >> 2) + 4 * ks;
                    int co = cog * 64 + m * 32 + row;
                    float2 c2 = BNc[512 + co];
                    float rd = fmaxf(acc[m][p][r] * c2.x + c2.y, 0.f);
                    float rp = ep[ph * 4096 + (m * 32 + row) * 64 + p * 32 + col];
                    int pos = pgb * 128 + ph * 64 + p * 32 + col;
                    size_t oi = ((size_t)(n * 512 + co)) * 2048 + d * 256 + pos;
                    out[oi] = gm * (rp + rd) + x[oi];
                }
    }
}

// ---------------------------------------------------------------------------
extern "C" void kernel_launch(void* const* d_in, const int* in_sizes, int n_in,
                              void* d_out, int out_size, void* d_ws, size_t ws_size,
                              hipStream_t stream)
{
    const float* x    = (const float*)d_in[0];
    const float* gama = (const float*)d_in[1];
    const float* Wq  = (const float*)d_in[2];
    const float* bq  = (const float*)d_in[3];
    const float* gq  = (const float*)d_in[4];
    const float* btq = (const float*)d_in[5];
    const float* mq  = (const float*)d_in[6];
    const float* vq  = (const float*)d_in[7];
    const float* Wk  = (const float*)d_in[8];
    const float* bk  = (const float*)d_in[9];
    const float* gk  = (const float*)d_in[10];
    const float* btk = (const float*)d_in[11];
    const float* mk  = (const float*)d_in[12];
    const float* vk  = (const float*)d_in[13];
    const float* Wv  = (const float*)d_in[14];
    const float* bv  = (const float*)d_in[15];
    const float* gv  = (const float*)d_in[16];
    const float* btv = (const float*)d_in[17];
    const float* mv  = (const float*)d_in[18];
    const float* vv  = (const float*)d_in[19];
    const float* Ws  = (const float*)d_in[20];
    const float* bs  = (const float*)d_in[21];
    const float* gs  = (const float*)d_in[22];
    const float* bts = (const float*)d_in[23];
    const float* ms  = (const float*)d_in[24];
    const float* vs  = (const float*)d_in[25];
    const float* Wd  = (const float*)d_in[26];
    const float* bd  = (const float*)d_in[27];
    const float* gd  = (const float*)d_in[28];
    const float* btd = (const float*)d_in[29];
    const float* md  = (const float*)d_in[30];
    const float* vd  = (const float*)d_in[31];

    char* ws = (char*)d_ws;
    unsigned short* Pp   = (unsigned short*)ws;                 // 829440 B
    unsigned short* Dp   = Pp + PADSZ;                          // 829440 B
    unsigned short* Wt   = Dp + PADSZ;                          // 3538944 B
    unsigned short* Wqkv = Wt + 2 * WTSZ;                       // 196608 B
    float* q = (float*)(ws + 5394432);
    float* k = q + QSZ;
    float* v = k + QSZ;
    float2* BNc = (float2*)(ws + 5394432 + 3 * 1048576);        // 8192 B

    prep_kernel<<<1625, 256, 0, stream>>>(
        Ws, Wd, Wq, Wk, Wv,
        bs, gs, bts, ms, vs,
        bd, gd, btd, md, vd,
        (uint4*)Pp, Wt, Wqkv, BNc);

    qkv_gemm_kernel<<<256, 256, 0, stream>>>(
        x, Wqkv,
        bq, gq, btq, mq, vq,
        bk, gk, btk, mk, vk,
        bv, gv, btv, mv, vv,
        q, k, v);

    att_kernel<<<1152, 256, 0, stream>>>(q, k, v, Pp, Dp);

    conv_fused_kernel<<<256, 256, 0, stream>>>(
        Pp, Dp, Wt, BNc,
        x, gama, (float*)d_out);
}